// Round 11
// baseline (919.624 us; speedup 1.0000x reference)
//
#include <hip/hip_runtime.h>
#include <hip/hip_bf16.h>
#include <stdint.h>

#define H 256
#define G 4096
#define TX 32     // kX tile rows
#define T0 64     // k0/kG tile rows

typedef __attribute__((ext_vector_type(8))) short bf16x8;
typedef __attribute__((ext_vector_type(4))) float f32x4;

__device__ inline short f2bf(float f){
  union { float f; uint32_t u; } v; v.f = f;
  uint32_t r = (v.u + 0x7FFFu + ((v.u >> 16) & 1u)) >> 16;
  return (short)(uint16_t)r;
}
__device__ inline float bf2f(short s){
  union { float f; uint32_t u; } v; v.u = ((uint32_t)(uint16_t)s) << 16;
  return v.f;
}
__device__ inline float sigmoidf_(float x){ return 1.f / (1.f + __expf(-x)); }

// ---------------- weight conversion f32 -> bf16 ----------------
__global__ void conv_w(const float* __restrict__ w1, const float* __restrict__ wih,
                       const float* __restrict__ whh,
                       short* __restrict__ o1, short* __restrict__ oih, short* __restrict__ ohh){
  int i = blockIdx.x * 256 + threadIdx.x;
  if (i < H*H) o1[i] = f2bf(w1[i]);
  if (i < 3*H*H){ oih[i] = f2bf(wih[i]); ohh[i] = f2bf(whh[i]); }
}

// ---------------- K0: mean-pool sums + counts + write x_bf16 ----------------
__global__ __launch_bounds__(512, 6) void k0_pool(const float* __restrict__ x, const int* __restrict__ batch,
                                                  float* __restrict__ pool, float* __restrict__ counts,
                                                  short* __restrict__ xbf, int nNodes){
  __shared__ int   ng[T0];
  __shared__ float Pacc[8][H];
  __shared__ float Cacc[8];
  __shared__ int   spanSh;

  const int t = threadIdx.x;
  const int base = blockIdx.x * T0;
  const int c4 = (t & 63) * 4;
  const int r0 = (t >> 6) * 8;   // 8 row-groups of 8 rows

  // issue the big loads FIRST so they overlap all setup
  float4 v[8];
  #pragma unroll
  for (int i = 0; i < 8; ++i){
    int node = base + r0 + i;
    if (node < nNodes) v[i] = *(const float4*)(x + (size_t)node*H + c4);
    else v[i] = make_float4(0.f,0.f,0.f,0.f);
  }

  if (t < T0) ng[t] = (base + t < nNodes) ? batch[base + t] : -1;
  for (int u = t; u < 8*H; u += 512) ((float*)Pacc)[u] = 0.f;
  if (t < 8) Cacc[t] = 0.f;
  __syncthreads();

  if (t == 64){
    int lg = ng[0];
    for (int i = 1; i < T0; ++i){ int g = ng[i]; if (g >= 0) lg = g; }
    spanSh = (ng[0] >= 0) ? (lg - ng[0]) : -1;
  }

  // write bf16 copy of x
  if (xbf){
    #pragma unroll
    for (int i = 0; i < 8; ++i){
      int node = base + r0 + i;
      if (node < nNodes){
        ushort4 o;
        o.x = (uint16_t)f2bf(v[i].x); o.y = (uint16_t)f2bf(v[i].y);
        o.z = (uint16_t)f2bf(v[i].z); o.w = (uint16_t)f2bf(v[i].w);
        *(ushort4*)(xbf + (size_t)node*H + c4) = o;
      }
    }
  }
  __syncthreads();

  const int g0 = ng[0];
  const bool useLds = (spanSh >= 0) && (spanSh < 8);

  float ax=0.f, ay=0.f, az=0.f, aw=0.f;
  int cur = ng[r0];
  if (cur >= 0){
    #pragma unroll
    for (int i = 0; i < 8; ++i){
      int g = ng[r0 + i];
      if (g < 0) break;
      if (g != cur){
        if (useLds){
          atomicAdd(&Pacc[cur-g0][c4], ax);   atomicAdd(&Pacc[cur-g0][c4+1], ay);
          atomicAdd(&Pacc[cur-g0][c4+2], az); atomicAdd(&Pacc[cur-g0][c4+3], aw);
        } else {
          atomicAdd(&pool[(size_t)cur*H + c4], ax);   atomicAdd(&pool[(size_t)cur*H + c4+1], ay);
          atomicAdd(&pool[(size_t)cur*H + c4+2], az); atomicAdd(&pool[(size_t)cur*H + c4+3], aw);
        }
        ax=ay=az=aw=0.f; cur = g;
      }
      ax += v[i].x; ay += v[i].y; az += v[i].z; aw += v[i].w;
    }
    if (useLds){
      atomicAdd(&Pacc[cur-g0][c4], ax);   atomicAdd(&Pacc[cur-g0][c4+1], ay);
      atomicAdd(&Pacc[cur-g0][c4+2], az); atomicAdd(&Pacc[cur-g0][c4+3], aw);
    } else {
      atomicAdd(&pool[(size_t)cur*H + c4], ax);   atomicAdd(&pool[(size_t)cur*H + c4+1], ay);
      atomicAdd(&pool[(size_t)cur*H + c4+2], az); atomicAdd(&pool[(size_t)cur*H + c4+3], aw);
    }
  }
  if (t < T0 && ng[t] >= 0){
    if (useLds) atomicAdd(&Cacc[ng[t]-g0], 1.f);
    else        atomicAdd(&counts[ng[t]], 1.f);
  }
  __syncthreads();

  if (useLds){
    int nr = spanSh + 1;
    for (int u = t; u < nr*H; u += 512){
      int r = u >> 8, c = u & 255;
      float vv = Pacc[r][c];
      if (vv != 0.f) atomicAdd(&pool[(size_t)(g0+r)*H + c], vv);
    }
    if (t < nr && Cacc[t] != 0.f) atomicAdd(&counts[g0 + t], Cacc[t]);
  }
}

// ---------------- K0b: repr = pool / max(counts,1) ----------------
__global__ void k0b_div(const float* __restrict__ pool, const float* __restrict__ counts,
                        float* __restrict__ repr){
  size_t i = (size_t)blockIdx.x * 256 + threadIdx.x;
  int g = (int)(i >> 8);
  repr[i] = pool[i] / fmaxf(counts[g], 1.f);
}

// ---------------- KT: hg[g] = W1 * bf16(repr[g]) + b1 ----------------
__global__ __launch_bounds__(256) void kT_hg(const float* __restrict__ repr,
    const short* __restrict__ w1bf, const float* __restrict__ b1,
    float* __restrict__ hg){
  __shared__ short Ar[16][H + 8];
  const int t    = threadIdx.x;
  const int wid  = t >> 6;
  const int lane = t & 63;
  const int l15  = lane & 15;
  const int l4   = lane >> 4;
  const int g0   = blockIdx.x * 16;

  for (int u = t; u < 16*32; u += 256){
    int row = u >> 5, cg = u & 31;
    int c0 = cg * 8;
    const float4* rp = (const float4*)(repr + (size_t)(g0+row)*H + c0);
    float4 r0 = rp[0], r1 = rp[1];
    bf16x8 o;
    o[0]=f2bf(r0.x); o[1]=f2bf(r0.y); o[2]=f2bf(r0.z); o[3]=f2bf(r0.w);
    o[4]=f2bf(r1.x); o[5]=f2bf(r1.y); o[6]=f2bf(r1.z); o[7]=f2bf(r1.w);
    *(bf16x8*)(&Ar[row][c0]) = o;
  }
  __syncthreads();

  f32x4 acc[4];
  #pragma unroll
  for (int i = 0; i < 4; ++i) acc[i] = (f32x4){0.f,0.f,0.f,0.f};
  #pragma unroll
  for (int kc = 0; kc < 8; ++kc){
    bf16x8 a = *(bf16x8*)(&Ar[l15][kc*32 + l4*8]);
    #pragma unroll
    for (int nt = 0; nt < 4; ++nt){
      int col = wid*64 + nt*16 + l15;
      bf16x8 b = *(const bf16x8*)(w1bf + (size_t)col*H + kc*32 + l4*8);
      acc[nt] = __builtin_amdgcn_mfma_f32_16x16x32_bf16(a, b, acc[nt], 0, 0, 0);
    }
  }
  #pragma unroll
  for (int nt = 0; nt < 4; ++nt){
    int col = wid*64 + nt*16 + l15;
    float b1v = b1[col];
    #pragma unroll
    for (int j = 0; j < 4; ++j){
      int row = l4*4 + j;
      hg[(size_t)(g0+row)*H + col] = acc[nt][j] + b1v;
    }
  }
}

// ---------------- KX: hx = W1 * bf16(x)  (ONE pass, timestep-invariant) ----------------
// Non-persistent: one 32-row x 128-col block per dispatch slot; 2 col-halves per tile.
// Adjacent-col B-fragment trick: Bf0 = W1 row (colB+2*l15), Bf1 = next row, so
// acc0/acc1 hold adjacent logical columns -> packed u32 stores (fully coalesced).
template<bool BF>
__global__ __launch_bounds__(256) void kX_hx(
    const float* __restrict__ xf32, const short* __restrict__ xbf,
    const short* __restrict__ w1bf, short* __restrict__ hx, int nNodes){

  __shared__ short Ain[TX][H + 8];   // 16.9 KB

  const int t    = threadIdx.x;
  const int wid  = t >> 6;           // 0..3
  const int lane = t & 63;
  const int l15  = lane & 15;
  const int l4   = lane >> 4;
  const int tile = blockIdx.x >> 1;
  const int ch   = blockIdx.x & 1;
  const int colB = ch*128 + wid*32;
  const int base = tile * TX;

  // 1. issue x loads FIRST (4 x 16B per thread, coalesced)
  bf16x8 xv[4];
  float4 xf[4][2];
  #pragma unroll
  for (int q = 0; q < 4; ++q){
    int u = t + q*256, row = u >> 5, cg = u & 31;
    int node = base + row;
    if constexpr (BF){
      xv[q] = (node < nNodes) ? *(const bf16x8*)(xbf + (size_t)node*H + cg*8) : (bf16x8)0;
    } else {
      if (node < nNodes){
        const float4* xp = (const float4*)(xf32 + (size_t)node*H + cg*8);
        xf[q][0] = xp[0]; xf[q][1] = xp[1];
      } else { xf[q][0] = make_float4(0.f,0.f,0.f,0.f); xf[q][1] = make_float4(0.f,0.f,0.f,0.f); }
    }
  }

  // 2. W1 fragments for adjacent col pair (L2-hot)
  bf16x8 Bf0[8], Bf1[8];
  {
    const short* wp0 = w1bf + (size_t)(colB + 2*l15)*H + l4*8;
    #pragma unroll
    for (int kc = 0; kc < 8; ++kc){
      Bf0[kc] = *(const bf16x8*)(wp0 + kc*32);
      Bf1[kc] = *(const bf16x8*)(wp0 + H + kc*32);
    }
  }

  // 3. stage tile
  #pragma unroll
  for (int q = 0; q < 4; ++q){
    int u = t + q*256, row = u >> 5, cg = u & 31;
    bf16x8 o;
    if constexpr (BF) o = xv[q];
    else {
      float4 a = xf[q][0], c = xf[q][1];
      o[0]=f2bf(a.x); o[1]=f2bf(a.y); o[2]=f2bf(a.z); o[3]=f2bf(a.w);
      o[4]=f2bf(c.x); o[5]=f2bf(c.y); o[6]=f2bf(c.z); o[7]=f2bf(c.w);
    }
    *(bf16x8*)(&Ain[row][cg*8]) = o;
  }
  __syncthreads();

  // 4. MFMA: 32 rows x 32 cols (as 2 adjacent-col fragments)
  f32x4 acc0[2], acc1[2];
  #pragma unroll
  for (int r = 0; r < 2; ++r){ acc0[r] = (f32x4){0.f,0.f,0.f,0.f}; acc1[r] = (f32x4){0.f,0.f,0.f,0.f}; }
  #pragma unroll
  for (int kc = 0; kc < 8; ++kc){
    #pragma unroll
    for (int r = 0; r < 2; ++r){
      bf16x8 a = *(bf16x8*)(&Ain[r*16 + l15][kc*32 + l4*8]);
      acc0[r] = __builtin_amdgcn_mfma_f32_16x16x32_bf16(a, Bf0[kc], acc0[r], 0, 0, 0);
      acc1[r] = __builtin_amdgcn_mfma_f32_16x16x32_bf16(a, Bf1[kc], acc1[r], 0, 0, 0);
    }
  }

  // 5. packed stores: cols (colB+2*l15, +1) for 8 rows
  #pragma unroll
  for (int r = 0; r < 2; ++r)
    #pragma unroll
    for (int j = 0; j < 4; ++j){
      int node = base + r*16 + l4*4 + j;
      if (node < nNodes){
        uint32_t pk = (uint32_t)(uint16_t)f2bf(acc0[r][j]) |
                      ((uint32_t)(uint16_t)f2bf(acc1[r][j]) << 16);
        *(uint32_t*)(hx + (size_t)node*H + colB + 2*l15) = pk;
      }
    }
}

// ---------------- KG: fused gate score + weighted pooling (streaming, no GEMM) ----------------
// s[n] = sum_c w2[c]*relu(hx[n][c] + hg[g][c]);  gate = sigmoid(s+b2);  pool[g] += gate*x[n]
template<bool BF>
__global__ __launch_bounds__(512, 4) void kG(
    const float* __restrict__ xf32, const short* __restrict__ xbf,
    const short* __restrict__ hx, const int* __restrict__ batch,
    const float* __restrict__ hg, const float* __restrict__ w2,
    const float* __restrict__ b2p, float* __restrict__ pool, int nNodes){

  __shared__ int   ng[T0];
  __shared__ float gates[T0];
  __shared__ float w2s[H];
  __shared__ float Pacc[8][H];
  __shared__ int   spanSh;

  const int t = threadIdx.x;
  const int base = blockIdx.x * T0;

  // phase-B (pooling) loads issued first
  const int c4 = (t & 63) * 4;
  const int r0 = (t >> 6) * 8;
  ushort4 u[8];
  float4  vf[8];
  #pragma unroll
  for (int i = 0; i < 8; ++i){
    int node = base + r0 + i;
    if constexpr (BF){
      u[i] = (node < nNodes) ? *(const ushort4*)(xbf + (size_t)node*H + c4)
                             : make_ushort4(0,0,0,0);
    } else {
      vf[i] = (node < nNodes) ? *(const float4*)(xf32 + (size_t)node*H + c4)
                              : make_float4(0.f,0.f,0.f,0.f);
    }
  }

  // phase-A loads: 8 threads per node, 32 cols each
  const int nodeA = base + (t >> 3);
  const int cseg  = (t & 7) * 32;
  const int gA    = (nodeA < nNodes) ? batch[nodeA] : -1;
  bf16x8 hxv[4];
  #pragma unroll
  for (int k = 0; k < 4; ++k)
    hxv[k] = (nodeA < nNodes) ? *(const bf16x8*)(hx + (size_t)nodeA*H + cseg + k*8) : (bf16x8)0;
  float4 hgv[8];
  #pragma unroll
  for (int k = 0; k < 8; ++k)
    hgv[k] = (gA >= 0) ? *(const float4*)(hg + (size_t)gA*H + cseg + k*4)
                       : make_float4(0.f,0.f,0.f,0.f);

  const float b2v = b2p[0];
  if (t < T0){
    int node = base + t;
    ng[t] = (node < nNodes) ? batch[node] : -1;
  }
  if (t < H) w2s[t] = w2[t];
  for (int w = t; w < 8*H; w += 512) ((float*)Pacc)[w] = 0.f;
  __syncthreads();

  if (t == 64){
    int lg = ng[0];
    for (int i = 1; i < T0; ++i){ int g = ng[i]; if (g >= 0) lg = g; }
    spanSh = (ng[0] >= 0) ? (lg - ng[0]) : -1;
  }

  // phase A: score partial over this thread's 32 cols (all indices static)
  float s = 0.f;
  if (gA >= 0){
    #pragma unroll
    for (int k = 0; k < 32; ++k){
      float hgk;
      {
        float4 q4 = hgv[k >> 2];
        hgk = (k & 3) == 0 ? q4.x : (k & 3) == 1 ? q4.y : (k & 3) == 2 ? q4.z : q4.w;
      }
      float hv = bf2f(hxv[k >> 3][k & 7]) + hgk;
      s += w2s[cseg + k] * fmaxf(hv, 0.f);
    }
  }
  s += __shfl_xor(s, 1);
  s += __shfl_xor(s, 2);
  s += __shfl_xor(s, 4);
  if ((t & 7) == 0) gates[t >> 3] = (gA >= 0) ? sigmoidf_(s + b2v) : 0.f;
  __syncthreads();

  // phase B: run-length weighted pooling (k1b pattern)
  const int g0 = ng[0];
  const bool useLds = (spanSh >= 0) && (spanSh < 8);

  float ax=0.f, ay=0.f, az=0.f, aw=0.f;
  int cur = ng[r0];
  if (cur >= 0){
    #pragma unroll
    for (int i = 0; i < 8; ++i){
      int g = ng[r0 + i];
      if (g < 0) break;
      if (g != cur){
        if (useLds){
          atomicAdd(&Pacc[cur-g0][c4], ax);   atomicAdd(&Pacc[cur-g0][c4+1], ay);
          atomicAdd(&Pacc[cur-g0][c4+2], az); atomicAdd(&Pacc[cur-g0][c4+3], aw);
        } else {
          atomicAdd(&pool[(size_t)cur*H + c4], ax);   atomicAdd(&pool[(size_t)cur*H + c4+1], ay);
          atomicAdd(&pool[(size_t)cur*H + c4+2], az); atomicAdd(&pool[(size_t)cur*H + c4+3], aw);
        }
        ax=ay=az=aw=0.f; cur = g;
      }
      float gv = gates[r0 + i];
      if constexpr (BF){
        ax += gv * bf2f((short)u[i].x); ay += gv * bf2f((short)u[i].y);
        az += gv * bf2f((short)u[i].z); aw += gv * bf2f((short)u[i].w);
      } else {
        ax += gv * bf2f(f2bf(vf[i].x)); ay += gv * bf2f(f2bf(vf[i].y));
        az += gv * bf2f(f2bf(vf[i].z)); aw += gv * bf2f(f2bf(vf[i].w));
      }
    }
    if (useLds){
      atomicAdd(&Pacc[cur-g0][c4], ax);   atomicAdd(&Pacc[cur-g0][c4+1], ay);
      atomicAdd(&Pacc[cur-g0][c4+2], az); atomicAdd(&Pacc[cur-g0][c4+3], aw);
    } else {
      atomicAdd(&pool[(size_t)cur*H + c4], ax);   atomicAdd(&pool[(size_t)cur*H + c4+1], ay);
      atomicAdd(&pool[(size_t)cur*H + c4+2], az); atomicAdd(&pool[(size_t)cur*H + c4+3], aw);
    }
  }
  __syncthreads();

  if (useLds){
    int nr = spanSh + 1;
    for (int w = t; w < nr*H; w += 512){
      int r = w >> 8, c = w & 255;
      float vv = Pacc[r][c];
      if (vv != 0.f) atomicAdd(&pool[(size_t)(g0+r)*H + c], vv);
    }
  }
}

// ---------------- K2: fused GRU over 16 graphs/block ----------------
__global__ __launch_bounds__(256) void k2_gru(const float* __restrict__ pool,
    const float* __restrict__ counts, const float* __restrict__ repr_in,
    const short* __restrict__ wihbf, const short* __restrict__ whhbf,
    const float* __restrict__ bih, const float* __restrict__ bhh,
    float* __restrict__ repr_out){

  __shared__ short Anew[16][H + 8];
  __shared__ short Aold[16][H + 8];
  __shared__ float hold[16][H];
  __shared__ float srz[16][2*H];
  __shared__ float sni[16][H];
  __shared__ float snh[16][H];

  const int t    = threadIdx.x;
  const int wid  = t >> 6;
  const int lane = t & 63;
  const int l15  = lane & 15;
  const int l4   = lane >> 4;
  const int g0   = blockIdx.x * 16;

  for (int u = t; u < 16*H; u += 256){
    int row = u >> 8, c = u & 255;
    int g = g0 + row;
    float cnt = fmaxf(counts[g], 1.f);
    float rin = repr_in[(size_t)g*H + c];
    float nr  = pool[(size_t)g*H + c] / cnt;
    Anew[row][c] = f2bf(nr);
    Aold[row][c] = f2bf(rin);
    hold[row][c] = rin;
  }
  __syncthreads();

  f32x4 ai[12], ah[12];
  #pragma unroll
  for (int i = 0; i < 12; ++i){ ai[i] = (f32x4){0.f,0.f,0.f,0.f}; ah[i] = (f32x4){0.f,0.f,0.f,0.f}; }

  for (int kc = 0; kc < 8; ++kc){
    bf16x8 an = *(bf16x8*)(&Anew[l15][kc*32 + l4*8]);
    bf16x8 ao = *(bf16x8*)(&Aold[l15][kc*32 + l4*8]);
    #pragma unroll
    for (int nt = 0; nt < 12; ++nt){
      int n = wid*192 + nt*16 + l15;
      bf16x8 bi = *(const bf16x8*)(wihbf + (size_t)n*H + kc*32 + l4*8);
      bf16x8 bh = *(const bf16x8*)(whhbf + (size_t)n*H + kc*32 + l4*8);
      ai[nt] = __builtin_amdgcn_mfma_f32_16x16x32_bf16(an, bi, ai[nt], 0, 0, 0);
      ah[nt] = __builtin_amdgcn_mfma_f32_16x16x32_bf16(ao, bh, ah[nt], 0, 0, 0);
    }
  }

  #pragma unroll
  for (int nt = 0; nt < 12; ++nt){
    int n = wid*192 + nt*16 + l15;
    float bi = bih[n], bh = bhh[n];
    #pragma unroll
    for (int r = 0; r < 4; ++r){
      int row = l4*4 + r;
      float si = ai[nt][r] + bi;
      float sh = ah[nt][r] + bh;
      if (n < 2*H) srz[row][n] = si + sh;
      else { sni[row][n - 2*H] = si; snh[row][n - 2*H] = sh; }
    }
  }
  __syncthreads();

  for (int u = t; u < 16*H; u += 256){
    int row = u >> 8, c = u & 255;
    float rr = sigmoidf_(srz[row][c]);
    float zz = sigmoidf_(srz[row][H + c]);
    float nn = tanhf(sni[row][c] + rr * snh[row][c]);
    float hv = (1.f - zz) * nn + zz * hold[row][c];
    repr_out[(size_t)(g0 + row)*H + c] = fmaxf(hv, 0.f);
  }
}

extern "C" void kernel_launch(void* const* d_in, const int* in_sizes, int n_in,
                              void* d_out, int out_size, void* d_ws, size_t ws_size,
                              hipStream_t stream){
  const float* x    = (const float*)d_in[0];
  const float* w1   = (const float*)d_in[1];
  const float* b1   = (const float*)d_in[2];
  const float* w2   = (const float*)d_in[3];
  const float* b2   = (const float*)d_in[4];
  const float* wih  = (const float*)d_in[5];
  const float* whh  = (const float*)d_in[6];
  const float* bih  = (const float*)d_in[7];
  const float* bhh  = (const float*)d_in[8];
  const int*   batch= (const int*)d_in[9];
  const int N = in_sizes[9];

  char* ws = (char*)d_ws;
  short* w1bf   = (short*)(ws + 0);            // 128 KB
  short* wihbf  = (short*)(ws + (1u<<17));     // 384 KB @128K
  short* whhbf  = (short*)(ws + (1u<<19));     // 384 KB @512K
  float* counts = (float*)(ws + 917504);       // 16 KB @896K
  float* pool   = (float*)(ws + (1u<<20));     // 4 MB @1M
  float* repr   = (float*)(ws + (1u<<20) + (1u<<22)); // 4 MB @5M
  float* hg     = (float*)d_out;               // 4 MB, dead before final k2 writes output
  float* outp   = (float*)d_out;

  const size_t XBF_OFF = (size_t)16u << 20;              // 16 MB
  const size_t xhBytes = (size_t)N * H * sizeof(short);  // 256 MB
  const size_t HX_OFF  = XBF_OFF + (((xhBytes + (1u<<20) - 1) >> 20) << 20);

  // big path: xbf + hx both fit; small path: hx only (read x as f32 everywhere)
  const bool useXbf = ws_size >= HX_OFF + xhBytes;
  short* xbf = useXbf ? (short*)(ws + XBF_OFF) : nullptr;
  short* hx  = useXbf ? (short*)(ws + HX_OFF) : (short*)(ws + XBF_OFF);

  const int nTiles32 = (N + TX - 1) / TX;      // 15625
  const int nBlk0    = (N + T0 - 1) / T0;      // 7813

  conv_w<<<768, 256, 0, stream>>>(w1, wih, whh, w1bf, wihbf, whhbf);

  hipMemsetAsync(counts, 0, G*sizeof(float), stream);
  hipMemsetAsync(pool, 0, (size_t)G*H*sizeof(float), stream);
  k0_pool<<<nBlk0, 512, 0, stream>>>(x, batch, pool, counts, xbf, N);
  k0b_div<<<G*H/256, 256, 0, stream>>>(pool, counts, repr);

  // hx = W1 * bf16(x)  -- once, timestep-invariant
  if (useXbf)
    kX_hx<true><<<nTiles32*2, 256, 0, stream>>>(x, xbf, w1bf, hx, N);
  else
    kX_hx<false><<<nTiles32*2, 256, 0, stream>>>(x, xbf, w1bf, hx, N);

  for (int ts = 0; ts < 2; ++ts){
    kT_hg<<<G/16, 256, 0, stream>>>(repr, w1bf, b1, hg);
    hipMemsetAsync(pool, 0, (size_t)G*H*sizeof(float), stream);
    if (useXbf)
      kG<true><<<nBlk0, 512, 0, stream>>>(x, xbf, hx, batch, hg, w2, b2, pool, N);
    else
      kG<false><<<nBlk0, 512, 0, stream>>>(x, xbf, hx, batch, hg, w2, b2, pool, N);
    k2_gru<<<G/16, 256, 0, stream>>>(pool, counts, repr, wihbf, whhbf, bih, bhh,
                                     (ts == 0) ? repr : outp);
  }
}

// Round 12
// 761.694 us; speedup vs baseline: 1.2073x; 1.2073x over previous
//
#include <hip/hip_runtime.h>
#include <hip/hip_bf16.h>
#include <stdint.h>

#define H 256
#define G 4096
#define TK 32     // k1a tile rows
#define TP0 128   // k0/k1b tile rows

typedef __attribute__((ext_vector_type(8))) short bf16x8;
typedef __attribute__((ext_vector_type(4))) float f32x4;

__device__ inline short f2bf(float f){
  union { float f; uint32_t u; } v; v.f = f;
  uint32_t r = (v.u + 0x7FFFu + ((v.u >> 16) & 1u)) >> 16;
  return (short)(uint16_t)r;
}
__device__ inline float bf2f(short s){
  union { float f; uint32_t u; } v; v.u = ((uint32_t)(uint16_t)s) << 16;
  return v.f;
}
__device__ inline float sigmoidf_(float x){ return 1.f / (1.f + __expf(-x)); }

// LDS-only barrier: does NOT drain vmcnt, so in-flight global loads continue.
__device__ inline void ldsbar(){
  asm volatile("s_waitcnt lgkmcnt(0)" ::: "memory");
  __builtin_amdgcn_s_barrier();
}

// ---------------- weight conversion f32 -> bf16 ----------------
__global__ void conv_w(const float* __restrict__ w1, const float* __restrict__ wih,
                       const float* __restrict__ whh,
                       short* __restrict__ o1, short* __restrict__ oih, short* __restrict__ ohh){
  int i = blockIdx.x * 256 + threadIdx.x;
  if (i < H*H) o1[i] = f2bf(w1[i]);
  if (i < 3*H*H){ oih[i] = f2bf(wih[i]); ohh[i] = f2bf(whh[i]); }
}

// ---------------- K0: mean-pool sums + counts + write x_bf16 (128-row tiles) ----------------
__global__ __launch_bounds__(512) __attribute__((amdgpu_waves_per_eu(2, 8)))
void k0_pool(const float* __restrict__ x, const int* __restrict__ batch,
             float* __restrict__ pool, float* __restrict__ counts,
             short* __restrict__ xbf, int nNodes){
  __shared__ int   ng[TP0];
  __shared__ float Pacc[8][H];
  __shared__ float Cacc[8];
  __shared__ int   spanSh;

  const int t = threadIdx.x;
  const int base = blockIdx.x * TP0;
  const int c4 = (t & 63) * 4;
  const int r0 = (t >> 6) * 16;   // 8 row-groups of 16 rows

  // issue ALL 16 loads first: 256 B/thread in flight -> ILP-covered latency
  float4 v[16];
  #pragma unroll
  for (int i = 0; i < 16; ++i){
    int node = base + r0 + i;
    if (node < nNodes) v[i] = *(const float4*)(x + (size_t)node*H + c4);
    else v[i] = make_float4(0.f,0.f,0.f,0.f);
  }

  if (t < TP0) ng[t] = (base + t < nNodes) ? batch[base + t] : -1;
  for (int u = t; u < 8*H; u += 512) ((float*)Pacc)[u] = 0.f;
  if (t < 8) Cacc[t] = 0.f;
  __syncthreads();

  if (t == 0){
    int lg = ng[0];
    if (base + TP0 <= nNodes) lg = ng[TP0-1];
    else { for (int i = TP0-1; i > 0; --i){ if (ng[i] >= 0){ lg = ng[i]; break; } } }
    spanSh = (ng[0] >= 0) ? (lg - ng[0]) : -1;
  }

  // write bf16 copy of x
  if (xbf){
    #pragma unroll
    for (int i = 0; i < 16; ++i){
      int node = base + r0 + i;
      if (node < nNodes){
        ushort4 o;
        o.x = (uint16_t)f2bf(v[i].x); o.y = (uint16_t)f2bf(v[i].y);
        o.z = (uint16_t)f2bf(v[i].z); o.w = (uint16_t)f2bf(v[i].w);
        *(ushort4*)(xbf + (size_t)node*H + c4) = o;
      }
    }
  }
  __syncthreads();

  const int g0 = ng[0];
  const bool useLds = (spanSh >= 0) && (spanSh < 8);

  float ax=0.f, ay=0.f, az=0.f, aw=0.f;
  int cur = ng[r0];
  if (cur >= 0){
    #pragma unroll
    for (int i = 0; i < 16; ++i){
      int g = ng[r0 + i];
      if (g < 0) break;
      if (g != cur){
        if (useLds){
          atomicAdd(&Pacc[cur-g0][c4], ax);   atomicAdd(&Pacc[cur-g0][c4+1], ay);
          atomicAdd(&Pacc[cur-g0][c4+2], az); atomicAdd(&Pacc[cur-g0][c4+3], aw);
        } else {
          atomicAdd(&pool[(size_t)cur*H + c4], ax);   atomicAdd(&pool[(size_t)cur*H + c4+1], ay);
          atomicAdd(&pool[(size_t)cur*H + c4+2], az); atomicAdd(&pool[(size_t)cur*H + c4+3], aw);
        }
        ax=ay=az=aw=0.f; cur = g;
      }
      ax += v[i].x; ay += v[i].y; az += v[i].z; aw += v[i].w;
    }
    if (useLds){
      atomicAdd(&Pacc[cur-g0][c4], ax);   atomicAdd(&Pacc[cur-g0][c4+1], ay);
      atomicAdd(&Pacc[cur-g0][c4+2], az); atomicAdd(&Pacc[cur-g0][c4+3], aw);
    } else {
      atomicAdd(&pool[(size_t)cur*H + c4], ax);   atomicAdd(&pool[(size_t)cur*H + c4+1], ay);
      atomicAdd(&pool[(size_t)cur*H + c4+2], az); atomicAdd(&pool[(size_t)cur*H + c4+3], aw);
    }
  }
  if (t < TP0 && ng[t] >= 0){
    if (useLds) atomicAdd(&Cacc[ng[t]-g0], 1.f);
    else        atomicAdd(&counts[ng[t]], 1.f);
  }
  __syncthreads();

  if (useLds){
    int nr = spanSh + 1;
    for (int u = t; u < nr*H; u += 512){
      int r = u >> 8, c = u & 255;
      float vv = Pacc[r][c];
      if (vv != 0.f) atomicAdd(&pool[(size_t)(g0+r)*H + c], vv);
    }
    if (t < nr && Cacc[t] != 0.f) atomicAdd(&counts[g0 + t], Cacc[t]);
  }
}

// ---------------- K0b: repr = pool / max(counts,1) ----------------
__global__ void k0b_div(const float* __restrict__ pool, const float* __restrict__ counts,
                        float* __restrict__ repr){
  size_t i = (size_t)blockIdx.x * 256 + threadIdx.x;
  int g = (int)(i >> 8);
  repr[i] = pool[i] / fmaxf(counts[g], 1.f);
}

// ---------------- KT: hg[g] = W1 * bf16(repr[g]) + b1 ----------------
__global__ __launch_bounds__(256) void kT_hg(const float* __restrict__ repr,
    const short* __restrict__ w1bf, const float* __restrict__ b1,
    float* __restrict__ hg){
  __shared__ short Ar[16][H + 8];
  const int t    = threadIdx.x;
  const int wid  = t >> 6;
  const int lane = t & 63;
  const int l15  = lane & 15;
  const int l4   = lane >> 4;
  const int g0   = blockIdx.x * 16;

  for (int u = t; u < 16*32; u += 256){
    int row = u >> 5, cg = u & 31;
    int c0 = cg * 8;
    const float4* rp = (const float4*)(repr + (size_t)(g0+row)*H + c0);
    float4 r0 = rp[0], r1 = rp[1];
    bf16x8 o;
    o[0]=f2bf(r0.x); o[1]=f2bf(r0.y); o[2]=f2bf(r0.z); o[3]=f2bf(r0.w);
    o[4]=f2bf(r1.x); o[5]=f2bf(r1.y); o[6]=f2bf(r1.z); o[7]=f2bf(r1.w);
    *(bf16x8*)(&Ar[row][c0]) = o;
  }
  __syncthreads();

  f32x4 acc[4];
  #pragma unroll
  for (int i = 0; i < 4; ++i) acc[i] = (f32x4){0.f,0.f,0.f,0.f};
  #pragma unroll
  for (int kc = 0; kc < 8; ++kc){
    bf16x8 a = *(bf16x8*)(&Ar[l15][kc*32 + l4*8]);
    #pragma unroll
    for (int nt = 0; nt < 4; ++nt){
      int col = wid*64 + nt*16 + l15;
      bf16x8 b = *(const bf16x8*)(w1bf + (size_t)col*H + kc*32 + l4*8);
      acc[nt] = __builtin_amdgcn_mfma_f32_16x16x32_bf16(a, b, acc[nt], 0, 0, 0);
    }
  }
  #pragma unroll
  for (int nt = 0; nt < 4; ++nt){
    int col = wid*64 + nt*16 + l15;
    float b1v = b1[col];
    #pragma unroll
    for (int j = 0; j < 4; ++j){
      int row = l4*4 + j;
      hg[(size_t)(g0+row)*H + col] = acc[nt][j] + b1v;
    }
  }
}

// ---------------- K1a: gate scores, col-split persistent GEMM (unchanged from R10) ----------------
template<bool BF>
__global__ __launch_bounds__(256) __attribute__((amdgpu_waves_per_eu(3, 4)))
void k1a_gate(
    const float* __restrict__ xf32, const short* __restrict__ xbf,
    const int* __restrict__ batch, const float* __restrict__ hg,
    const short* __restrict__ w1bf, const float* __restrict__ w2,
    float* __restrict__ sgate,
    int nNodes, int nTiles, int nChains){

  __shared__ short Ain[2][TK][H + 8];   // 33.8 KB double-buffered x tiles
  __shared__ int   ngS[2][TK];

  const int t    = threadIdx.x;
  const int wid  = t >> 6;      // 0..3
  const int lane = t & 63;
  const int l15  = lane & 15;
  const int l4   = lane >> 4;

  const int ch    = blockIdx.x >= nChains;
  const int chain = ch ? blockIdx.x - nChains : blockIdx.x;
  const int colB  = ch*128 + wid*32;

  const int tile0 = (int)(((long long)chain * nTiles) / nChains);
  const int tile1 = (int)(((long long)(chain+1) * nTiles) / nChains);
  if (tile0 >= tile1) return;

  bf16x8 Bf0[8], Bf1[8];
  {
    const short* wp0 = w1bf + (size_t)(colB + l15)*H + l4*8;
    #pragma unroll
    for (int kc = 0; kc < 8; ++kc){
      Bf0[kc] = *(const bf16x8*)(wp0 + kc*32);
      Bf1[kc] = *(const bf16x8*)(wp0 + 16*H + kc*32);
    }
  }
  const float w2v0 = w2[colB + l15];
  const float w2v1 = w2[colB + 16 + l15];

  const int srow = t >> 5;
  const int scol = (t & 31) * 8;
  bf16x8 xv[4];
  float4 xf[4][2];
  int ngv = -1;

  auto issueT = [&](int tile){
    int base = tile * TK;
    #pragma unroll
    for (int q = 0; q < 4; ++q){
      int node = base + srow + q*8;
      if constexpr (BF){
        xv[q] = (node < nNodes) ? *(const bf16x8*)(xbf + (size_t)node*H + scol) : (bf16x8)0;
      } else {
        if (node < nNodes){
          const float4* xp = (const float4*)(xf32 + (size_t)node*H + scol);
          xf[q][0] = xp[0]; xf[q][1] = xp[1];
        } else { xf[q][0] = make_float4(0.f,0.f,0.f,0.f); xf[q][1] = make_float4(0.f,0.f,0.f,0.f); }
      }
    }
    if (t < TK){
      int node = base + t;
      ngv = (node < nNodes) ? batch[node] : -1;
    }
  };
  auto stageT = [&](int buf){
    #pragma unroll
    for (int q = 0; q < 4; ++q){
      bf16x8 o;
      if constexpr (BF) o = xv[q];
      else {
        float4 a = xf[q][0], c = xf[q][1];
        o[0]=f2bf(a.x); o[1]=f2bf(a.y); o[2]=f2bf(a.z); o[3]=f2bf(a.w);
        o[4]=f2bf(c.x); o[5]=f2bf(c.y); o[6]=f2bf(c.z); o[7]=f2bf(c.w);
      }
      *(bf16x8*)(&Ain[buf][srow + q*8][scol]) = o;
    }
    if (t < TK) ngS[buf][t] = ngv;
  };

  issueT(tile0);
  stageT(0);
  if (tile0 + 1 < tile1) issueT(tile0 + 1);

  int cur = 0;
  for (int tile = tile0; tile < tile1; ++tile, cur ^= 1){
    ldsbar();

    int gr[2][4];
    float hv0[2][4], hv1[2][4];
    #pragma unroll
    for (int r = 0; r < 2; ++r)
      #pragma unroll
      for (int j = 0; j < 4; ++j){
        int g = ngS[cur][r*16 + l4*4 + j];
        gr[r][j] = g;
        if (g >= 0){
          const float* hgr = hg + (size_t)g*H + colB;
          hv0[r][j] = hgr[l15]; hv1[r][j] = hgr[16 + l15];
        } else { hv0[r][j] = 0.f; hv1[r][j] = 0.f; }
      }

    f32x4 acc0[2], acc1[2];
    #pragma unroll
    for (int r = 0; r < 2; ++r){ acc0[r] = (f32x4){0.f,0.f,0.f,0.f}; acc1[r] = (f32x4){0.f,0.f,0.f,0.f}; }
    #pragma unroll
    for (int kc = 0; kc < 8; ++kc){
      #pragma unroll
      for (int r = 0; r < 2; ++r){
        bf16x8 a = *(bf16x8*)(&Ain[cur][r*16 + l15][kc*32 + l4*8]);
        acc0[r] = __builtin_amdgcn_mfma_f32_16x16x32_bf16(a, Bf0[kc], acc0[r], 0, 0, 0);
        acc1[r] = __builtin_amdgcn_mfma_f32_16x16x32_bf16(a, Bf1[kc], acc1[r], 0, 0, 0);
      }
    }

    if (tile + 1 < tile1){
      stageT(cur ^ 1);
      if (tile + 2 < tile1) issueT(tile + 2);
    }

    float p[2][4];
    #pragma unroll
    for (int r = 0; r < 2; ++r)
      #pragma unroll
      for (int j = 0; j < 4; ++j){
        float h0 = fmaxf(acc0[r][j] + hv0[r][j], 0.f);
        float h1 = fmaxf(acc1[r][j] + hv1[r][j], 0.f);
        p[r][j] = w2v0*h0 + w2v1*h1;
      }
    #pragma unroll
    for (int off = 1; off < 16; off <<= 1){
      #pragma unroll
      for (int r = 0; r < 2; ++r)
        #pragma unroll
        for (int j = 0; j < 4; ++j) p[r][j] += __shfl_xor(p[r][j], off);
    }
    if (l15 == 0){
      int base = tile * TK;
      #pragma unroll
      for (int r = 0; r < 2; ++r)
        #pragma unroll
        for (int j = 0; j < 4; ++j){
          if (gr[r][j] >= 0)
            atomicAdd(&sgate[base + r*16 + l4*4 + j], p[r][j]);
        }
    }
  }
}

// ---------------- K1b: streaming weighted pooling (128-row tiles) ----------------
template<bool BF>
__global__ __launch_bounds__(512) __attribute__((amdgpu_waves_per_eu(2, 8)))
void k1b_pool(
    const float* __restrict__ xf32, const short* __restrict__ xbf,
    const int* __restrict__ batch, const float* __restrict__ sgate,
    const float* __restrict__ b2p, float* __restrict__ pool, int nNodes){

  __shared__ int   ng[TP0];
  __shared__ float gs[TP0];
  __shared__ float Pacc[8][H];
  __shared__ int   spanSh;

  const int t = threadIdx.x;
  const int base = blockIdx.x * TP0;
  const int c4 = (t & 63) * 4;
  const int r0 = (t >> 6) * 16;

  // issue all 16 x loads first
  ushort4 u[16];
  float4  vf[16];
  #pragma unroll
  for (int i = 0; i < 16; ++i){
    int node = base + r0 + i;
    if constexpr (BF){
      u[i] = (node < nNodes) ? *(const ushort4*)(xbf + (size_t)node*H + c4)
                             : make_ushort4(0,0,0,0);
    } else {
      vf[i] = (node < nNodes) ? *(const float4*)(xf32 + (size_t)node*H + c4)
                              : make_float4(0.f,0.f,0.f,0.f);
    }
  }

  const float b2v = b2p[0];
  if (t < TP0){
    int node = base + t;
    if (node < nNodes){
      ng[t] = batch[node];
      gs[t] = sigmoidf_(sgate[node] + b2v);
    } else { ng[t] = -1; gs[t] = 0.f; }
  }
  for (int w = t; w < 8*H; w += 512) ((float*)Pacc)[w] = 0.f;
  __syncthreads();

  if (t == 0){
    int lg = ng[0];
    if (base + TP0 <= nNodes) lg = ng[TP0-1];
    else { for (int i = TP0-1; i > 0; --i){ if (ng[i] >= 0){ lg = ng[i]; break; } } }
    spanSh = (ng[0] >= 0) ? (lg - ng[0]) : -1;
  }
  __syncthreads();

  const int g0 = ng[0];
  const bool useLds = (spanSh >= 0) && (spanSh < 8);

  float ax=0.f, ay=0.f, az=0.f, aw=0.f;
  int cur = ng[r0];
  if (cur >= 0){
    #pragma unroll
    for (int i = 0; i < 16; ++i){
      int g = ng[r0 + i];
      if (g < 0) break;
      if (g != cur){
        if (useLds){
          atomicAdd(&Pacc[cur-g0][c4], ax);   atomicAdd(&Pacc[cur-g0][c4+1], ay);
          atomicAdd(&Pacc[cur-g0][c4+2], az); atomicAdd(&Pacc[cur-g0][c4+3], aw);
        } else {
          atomicAdd(&pool[(size_t)cur*H + c4], ax);   atomicAdd(&pool[(size_t)cur*H + c4+1], ay);
          atomicAdd(&pool[(size_t)cur*H + c4+2], az); atomicAdd(&pool[(size_t)cur*H + c4+3], aw);
        }
        ax=ay=az=aw=0.f; cur = g;
      }
      float gv = gs[r0 + i];
      if constexpr (BF){
        ax += gv * bf2f((short)u[i].x); ay += gv * bf2f((short)u[i].y);
        az += gv * bf2f((short)u[i].z); aw += gv * bf2f((short)u[i].w);
      } else {
        ax += gv * bf2f(f2bf(vf[i].x)); ay += gv * bf2f(f2bf(vf[i].y));
        az += gv * bf2f(f2bf(vf[i].z)); aw += gv * bf2f(f2bf(vf[i].w));
      }
    }
    if (useLds){
      atomicAdd(&Pacc[cur-g0][c4], ax);   atomicAdd(&Pacc[cur-g0][c4+1], ay);
      atomicAdd(&Pacc[cur-g0][c4+2], az); atomicAdd(&Pacc[cur-g0][c4+3], aw);
    } else {
      atomicAdd(&pool[(size_t)cur*H + c4], ax);   atomicAdd(&pool[(size_t)cur*H + c4+1], ay);
      atomicAdd(&pool[(size_t)cur*H + c4+2], az); atomicAdd(&pool[(size_t)cur*H + c4+3], aw);
    }
  }
  __syncthreads();

  if (useLds){
    int nr = spanSh + 1;
    for (int w = t; w < nr*H; w += 512){
      int r = w >> 8, c = w & 255;
      float vv = Pacc[r][c];
      if (vv != 0.f) atomicAdd(&pool[(size_t)(g0+r)*H + c], vv);
    }
  }
}

// ---------------- K2: fused GRU over 16 graphs/block ----------------
__global__ __launch_bounds__(256) void k2_gru(const float* __restrict__ pool,
    const float* __restrict__ counts, const float* __restrict__ repr_in,
    const short* __restrict__ wihbf, const short* __restrict__ whhbf,
    const float* __restrict__ bih, const float* __restrict__ bhh,
    float* __restrict__ repr_out){

  __shared__ short Anew[16][H + 8];
  __shared__ short Aold[16][H + 8];
  __shared__ float hold[16][H];
  __shared__ float srz[16][2*H];
  __shared__ float sni[16][H];
  __shared__ float snh[16][H];

  const int t    = threadIdx.x;
  const int wid  = t >> 6;
  const int lane = t & 63;
  const int l15  = lane & 15;
  const int l4   = lane >> 4;
  const int g0   = blockIdx.x * 16;

  for (int u = t; u < 16*H; u += 256){
    int row = u >> 8, c = u & 255;
    int g = g0 + row;
    float cnt = fmaxf(counts[g], 1.f);
    float rin = repr_in[(size_t)g*H + c];
    float nr  = pool[(size_t)g*H + c] / cnt;
    Anew[row][c] = f2bf(nr);
    Aold[row][c] = f2bf(rin);
    hold[row][c] = rin;
  }
  __syncthreads();

  f32x4 ai[12], ah[12];
  #pragma unroll
  for (int i = 0; i < 12; ++i){ ai[i] = (f32x4){0.f,0.f,0.f,0.f}; ah[i] = (f32x4){0.f,0.f,0.f,0.f}; }

  for (int kc = 0; kc < 8; ++kc){
    bf16x8 an = *(bf16x8*)(&Anew[l15][kc*32 + l4*8]);
    bf16x8 ao = *(bf16x8*)(&Aold[l15][kc*32 + l4*8]);
    #pragma unroll
    for (int nt = 0; nt < 12; ++nt){
      int n = wid*192 + nt*16 + l15;
      bf16x8 bi = *(const bf16x8*)(wihbf + (size_t)n*H + kc*32 + l4*8);
      bf16x8 bh = *(const bf16x8*)(whhbf + (size_t)n*H + kc*32 + l4*8);
      ai[nt] = __builtin_amdgcn_mfma_f32_16x16x32_bf16(an, bi, ai[nt], 0, 0, 0);
      ah[nt] = __builtin_amdgcn_mfma_f32_16x16x32_bf16(ao, bh, ah[nt], 0, 0, 0);
    }
  }

  #pragma unroll
  for (int nt = 0; nt < 12; ++nt){
    int n = wid*192 + nt*16 + l15;
    float bi = bih[n], bh = bhh[n];
    #pragma unroll
    for (int r = 0; r < 4; ++r){
      int row = l4*4 + r;
      float si = ai[nt][r] + bi;
      float sh = ah[nt][r] + bh;
      if (n < 2*H) srz[row][n] = si + sh;
      else { sni[row][n - 2*H] = si; snh[row][n - 2*H] = sh; }
    }
  }
  __syncthreads();

  for (int u = t; u < 16*H; u += 256){
    int row = u >> 8, c = u & 255;
    float rr = sigmoidf_(srz[row][c]);
    float zz = sigmoidf_(srz[row][H + c]);
    float nn = tanhf(sni[row][c] + rr * snh[row][c]);
    float hv = (1.f - zz) * nn + zz * hold[row][c];
    repr_out[(size_t)(g0 + row)*H + c] = fmaxf(hv, 0.f);
  }
}

extern "C" void kernel_launch(void* const* d_in, const int* in_sizes, int n_in,
                              void* d_out, int out_size, void* d_ws, size_t ws_size,
                              hipStream_t stream){
  const float* x    = (const float*)d_in[0];
  const float* w1   = (const float*)d_in[1];
  const float* b1   = (const float*)d_in[2];
  const float* w2   = (const float*)d_in[3];
  const float* b2   = (const float*)d_in[4];
  const float* wih  = (const float*)d_in[5];
  const float* whh  = (const float*)d_in[6];
  const float* bih  = (const float*)d_in[7];
  const float* bhh  = (const float*)d_in[8];
  const int*   batch= (const int*)d_in[9];
  const int N = in_sizes[9];

  char* ws = (char*)d_ws;
  short* w1bf   = (short*)(ws + 0);            // 128 KB
  short* wihbf  = (short*)(ws + (1u<<17));     // 384 KB @128K
  short* whhbf  = (short*)(ws + (1u<<19));     // 384 KB @512K
  float* counts = (float*)(ws + 917504);       // 16 KB @896K
  float* pool   = (float*)(ws + (1u<<20));     // 4 MB @1M
  float* repr   = (float*)(ws + (1u<<20) + (1u<<22)); // 4 MB @5M
  float* sgate  = (float*)(ws + (9u<<20));     // 2 MB @9M
  float* hg     = (float*)d_out;               // 4 MB, dead before final k2 writes output
  float* outp   = (float*)d_out;

  const size_t XBF_OFF = (size_t)16u << 20;    // 16 MB
  const bool useXbf = ws_size >= XBF_OFF + (size_t)N * H * sizeof(short);
  short* xbf = useXbf ? (short*)(ws + XBF_OFF) : nullptr;

  const int nTiles  = (N + TK - 1) / TK;       // 15625
  const int nChains = 512;
  const int nBlk1a  = nChains * 2;             // 1024 blocks = 4/CU resident
  const int nBlkP   = (N + TP0 - 1) / TP0;     // 3907

  conv_w<<<768, 256, 0, stream>>>(w1, wih, whh, w1bf, wihbf, whhbf);

  hipMemsetAsync(counts, 0, G*sizeof(float), stream);
  hipMemsetAsync(pool, 0, (size_t)G*H*sizeof(float), stream);
  k0_pool<<<nBlkP, 512, 0, stream>>>(x, batch, pool, counts, xbf, N);
  k0b_div<<<G*H/256, 256, 0, stream>>>(pool, counts, repr);

  for (int ts = 0; ts < 2; ++ts){
    kT_hg<<<G/16, 256, 0, stream>>>(repr, w1bf, b1, hg);
    hipMemsetAsync(sgate, 0, (size_t)N*sizeof(float), stream);
    hipMemsetAsync(pool, 0, (size_t)G*H*sizeof(float), stream);
    if (useXbf){
      k1a_gate<true><<<nBlk1a, 256, 0, stream>>>(x, xbf, batch, hg, w1bf, w2, sgate, N, nTiles, nChains);
      k1b_pool<true><<<nBlkP, 512, 0, stream>>>(x, xbf, batch, sgate, b2, pool, N);
    } else {
      k1a_gate<false><<<nBlk1a, 256, 0, stream>>>(x, xbf, batch, hg, w1bf, w2, sgate, N, nTiles, nChains);
      k1b_pool<false><<<nBlkP, 512, 0, stream>>>(x, xbf, batch, sgate, b2, pool, N);
    }
    k2_gru<<<G/16, 256, 0, stream>>>(pool, counts, repr, wihbf, whhbf, bih, bhh,
                                     (ts == 0) ? repr : outp);
  }
}

// Round 13
// 746.662 us; speedup vs baseline: 1.2316x; 1.0201x over previous
//
#include <hip/hip_runtime.h>
#include <hip/hip_bf16.h>
#include <stdint.h>

#define H 256
#define G 4096
#define TK 32     // k1a tile rows
#define TP0 128   // k0/k1b tile rows

typedef __attribute__((ext_vector_type(8))) short bf16x8;
typedef __attribute__((ext_vector_type(4))) float f32x4;

__device__ inline short f2bf(float f){
  union { float f; uint32_t u; } v; v.f = f;
  uint32_t r = (v.u + 0x7FFFu + ((v.u >> 16) & 1u)) >> 16;
  return (short)(uint16_t)r;
}
__device__ inline float bf2f(short s){
  union { float f; uint32_t u; } v; v.u = ((uint32_t)(uint16_t)s) << 16;
  return v.f;
}
__device__ inline uint32_t pk2(float lo, float hi){
  return (uint32_t)(uint16_t)f2bf(lo) | ((uint32_t)(uint16_t)f2bf(hi) << 16);
}
__device__ inline float sigmoidf_(float x){ return 1.f / (1.f + __expf(-x)); }

// LDS-only barrier: does NOT drain vmcnt, so in-flight global loads continue.
__device__ inline void ldsbar(){
  asm volatile("s_waitcnt lgkmcnt(0)" ::: "memory");
  __builtin_amdgcn_s_barrier();
}

// ---------------- conv_w: weight bf16 conversion + zero counts/pool ----------------
__global__ void conv_w(const float* __restrict__ w1, const float* __restrict__ wih,
                       const float* __restrict__ whh,
                       short* __restrict__ o1, short* __restrict__ oih, short* __restrict__ ohh,
                       float* __restrict__ counts, float* __restrict__ pool){
  int i = blockIdx.x * 256 + threadIdx.x;
  if (i < H*H) o1[i] = f2bf(w1[i]);
  if (i < 3*H*H){ oih[i] = f2bf(wih[i]); ohh[i] = f2bf(whh[i]); }
  if (i < G) counts[i] = 0.f;
  for (int j = i; j < G*H; j += 768*256) pool[j] = 0.f;
}

// ---------------- K0: mean-pool sums + counts + write x_bf16 + zero sgate ----------------
__global__ __launch_bounds__(512) __attribute__((amdgpu_waves_per_eu(2, 8)))
void k0_pool(const float* __restrict__ x, const int* __restrict__ batch,
             float* __restrict__ pool, float* __restrict__ counts,
             short* __restrict__ xbf, float* __restrict__ sgate, int nNodes){
  __shared__ int   ng[TP0];
  __shared__ float Pacc[8][H];
  __shared__ float Cacc[8];
  __shared__ int   spanSh;

  const int t = threadIdx.x;
  const int base = blockIdx.x * TP0;
  const int c4 = (t & 63) * 4;
  const int r0 = (t >> 6) * 16;   // 8 row-groups of 16 rows

  // issue ALL 16 loads first: 256 B/thread in flight -> ILP-covered latency
  float4 v[16];
  #pragma unroll
  for (int i = 0; i < 16; ++i){
    int node = base + r0 + i;
    if (node < nNodes) v[i] = *(const float4*)(x + (size_t)node*H + c4);
    else v[i] = make_float4(0.f,0.f,0.f,0.f);
  }

  { int gi = blockIdx.x * 512 + t; if (gi < nNodes) sgate[gi] = 0.f; }

  if (t < TP0) ng[t] = (base + t < nNodes) ? batch[base + t] : -1;
  for (int u = t; u < 8*H; u += 512) ((float*)Pacc)[u] = 0.f;
  if (t < 8) Cacc[t] = 0.f;
  __syncthreads();

  if (t == 0){
    int lg = ng[0];
    if (base + TP0 <= nNodes) lg = ng[TP0-1];
    else { for (int i = TP0-1; i > 0; --i){ if (ng[i] >= 0){ lg = ng[i]; break; } } }
    spanSh = (ng[0] >= 0) ? (lg - ng[0]) : -1;
  }

  // write bf16 copy of x
  if (xbf){
    #pragma unroll
    for (int i = 0; i < 16; ++i){
      int node = base + r0 + i;
      if (node < nNodes){
        ushort4 o;
        o.x = (uint16_t)f2bf(v[i].x); o.y = (uint16_t)f2bf(v[i].y);
        o.z = (uint16_t)f2bf(v[i].z); o.w = (uint16_t)f2bf(v[i].w);
        *(ushort4*)(xbf + (size_t)node*H + c4) = o;
      }
    }
  }
  __syncthreads();

  const int g0 = ng[0];
  const bool useLds = (spanSh >= 0) && (spanSh < 8);

  float ax=0.f, ay=0.f, az=0.f, aw=0.f;
  int cur = ng[r0];
  if (cur >= 0){
    #pragma unroll
    for (int i = 0; i < 16; ++i){
      int g = ng[r0 + i];
      if (g < 0) break;
      if (g != cur){
        if (useLds){
          atomicAdd(&Pacc[cur-g0][c4], ax);   atomicAdd(&Pacc[cur-g0][c4+1], ay);
          atomicAdd(&Pacc[cur-g0][c4+2], az); atomicAdd(&Pacc[cur-g0][c4+3], aw);
        } else {
          atomicAdd(&pool[(size_t)cur*H + c4], ax);   atomicAdd(&pool[(size_t)cur*H + c4+1], ay);
          atomicAdd(&pool[(size_t)cur*H + c4+2], az); atomicAdd(&pool[(size_t)cur*H + c4+3], aw);
        }
        ax=ay=az=aw=0.f; cur = g;
      }
      ax += v[i].x; ay += v[i].y; az += v[i].z; aw += v[i].w;
    }
    if (useLds){
      atomicAdd(&Pacc[cur-g0][c4], ax);   atomicAdd(&Pacc[cur-g0][c4+1], ay);
      atomicAdd(&Pacc[cur-g0][c4+2], az); atomicAdd(&Pacc[cur-g0][c4+3], aw);
    } else {
      atomicAdd(&pool[(size_t)cur*H + c4], ax);   atomicAdd(&pool[(size_t)cur*H + c4+1], ay);
      atomicAdd(&pool[(size_t)cur*H + c4+2], az); atomicAdd(&pool[(size_t)cur*H + c4+3], aw);
    }
  }
  if (t < TP0 && ng[t] >= 0){
    if (useLds) atomicAdd(&Cacc[ng[t]-g0], 1.f);
    else        atomicAdd(&counts[ng[t]], 1.f);
  }
  __syncthreads();

  if (useLds){
    int nr = spanSh + 1;
    for (int u = t; u < nr*H; u += 512){
      int r = u >> 8, c = u & 255;
      float vv = Pacc[r][c];
      if (vv != 0.f) atomicAdd(&pool[(size_t)(g0+r)*H + c], vv);
    }
    if (t < nr && Cacc[t] != 0.f) atomicAdd(&counts[g0 + t], Cacc[t]);
  }
}

// ---------------- K0b: repr = pool / max(counts,1) ; zeroes pool ----------------
__global__ void k0b_div(const float* __restrict__ pool, const float* __restrict__ counts,
                        float* __restrict__ repr, float* __restrict__ pool_mut){
  size_t i = (size_t)blockIdx.x * 256 + threadIdx.x;
  int g = (int)(i >> 8);
  repr[i] = pool[i] / fmaxf(counts[g], 1.f);
  pool_mut[i] = 0.f;
}

// ---------------- KT: hgp[g] = packed bf16 pairs of W1*bf16(repr[g]) + b1 ----------------
__global__ __launch_bounds__(256) void kT_hg(const float* __restrict__ repr,
    const short* __restrict__ w1bf, const float* __restrict__ b1,
    uint32_t* __restrict__ hgp){
  __shared__ short Ar[16][H + 8];
  const int t    = threadIdx.x;
  const int wid  = t >> 6;
  const int lane = t & 63;
  const int l15  = lane & 15;
  const int l4   = lane >> 4;
  const int g0   = blockIdx.x * 16;

  for (int u = t; u < 16*32; u += 256){
    int row = u >> 5, cg = u & 31;
    int c0 = cg * 8;
    const float4* rp = (const float4*)(repr + (size_t)(g0+row)*H + c0);
    float4 r0 = rp[0], r1 = rp[1];
    bf16x8 o;
    o[0]=f2bf(r0.x); o[1]=f2bf(r0.y); o[2]=f2bf(r0.z); o[3]=f2bf(r0.w);
    o[4]=f2bf(r1.x); o[5]=f2bf(r1.y); o[6]=f2bf(r1.z); o[7]=f2bf(r1.w);
    *(bf16x8*)(&Ar[row][c0]) = o;
  }
  __syncthreads();

  f32x4 acc[4];
  #pragma unroll
  for (int i = 0; i < 4; ++i) acc[i] = (f32x4){0.f,0.f,0.f,0.f};
  #pragma unroll
  for (int kc = 0; kc < 8; ++kc){
    bf16x8 a = *(bf16x8*)(&Ar[l15][kc*32 + l4*8]);
    #pragma unroll
    for (int nt = 0; nt < 4; ++nt){
      int col = wid*64 + nt*16 + l15;
      bf16x8 b = *(const bf16x8*)(w1bf + (size_t)col*H + kc*32 + l4*8);
      acc[nt] = __builtin_amdgcn_mfma_f32_16x16x32_bf16(a, b, acc[nt], 0, 0, 0);
    }
  }
  const float b1v0 = b1[wid*64 + l15];
  const float b1v1 = b1[wid*64 + 16 + l15];
  const float b1v2 = b1[wid*64 + 32 + l15];
  const float b1v3 = b1[wid*64 + 48 + l15];
  #pragma unroll
  for (int j = 0; j < 4; ++j){
    int row = l4*4 + j;
    hgp[(size_t)(g0+row)*128 + wid*32 + l15]      = pk2(acc[0][j]+b1v0, acc[1][j]+b1v1);
    hgp[(size_t)(g0+row)*128 + wid*32 + 16 + l15] = pk2(acc[2][j]+b1v2, acc[3][j]+b1v3);
  }
}

// ---------------- K1a: gate scores, col-split persistent GEMM ----------------
template<bool BF>
__global__ __launch_bounds__(256) __attribute__((amdgpu_waves_per_eu(3, 4)))
void k1a_gate(
    const float* __restrict__ xf32, const short* __restrict__ xbf,
    const int* __restrict__ batch, const uint32_t* __restrict__ hgp,
    const short* __restrict__ w1bf, const float* __restrict__ w2,
    float* __restrict__ sgate,
    int nNodes, int nTiles, int nChains){

  __shared__ short Ain[2][TK][H + 8];   // 33.8 KB double-buffered x tiles
  __shared__ int   ngS[2][TK];

  const int t    = threadIdx.x;
  const int wid  = t >> 6;      // 0..3
  const int lane = t & 63;
  const int l15  = lane & 15;
  const int l4   = lane >> 4;

  const int ch    = blockIdx.x >= nChains;
  const int chain = ch ? blockIdx.x - nChains : blockIdx.x;
  const int colB  = ch*128 + wid*32;
  const int hgcol = ch*64 + wid*16 + l15;   // packed-pair column index

  const int tile0 = (int)(((long long)chain * nTiles) / nChains);
  const int tile1 = (int)(((long long)(chain+1) * nTiles) / nChains);
  if (tile0 >= tile1) return;

  bf16x8 Bf0[8], Bf1[8];
  {
    const short* wp0 = w1bf + (size_t)(colB + l15)*H + l4*8;
    #pragma unroll
    for (int kc = 0; kc < 8; ++kc){
      Bf0[kc] = *(const bf16x8*)(wp0 + kc*32);
      Bf1[kc] = *(const bf16x8*)(wp0 + 16*H + kc*32);
    }
  }
  const float w2v0 = w2[colB + l15];
  const float w2v1 = w2[colB + 16 + l15];

  const int srow = t >> 5;
  const int scol = (t & 31) * 8;
  bf16x8 xv[4];
  float4 xf[4][2];
  int ngv = -1;

  auto issueT = [&](int tile){
    int base = tile * TK;
    #pragma unroll
    for (int q = 0; q < 4; ++q){
      int node = base + srow + q*8;
      if constexpr (BF){
        xv[q] = (node < nNodes) ? *(const bf16x8*)(xbf + (size_t)node*H + scol) : (bf16x8)0;
      } else {
        if (node < nNodes){
          const float4* xp = (const float4*)(xf32 + (size_t)node*H + scol);
          xf[q][0] = xp[0]; xf[q][1] = xp[1];
        } else { xf[q][0] = make_float4(0.f,0.f,0.f,0.f); xf[q][1] = make_float4(0.f,0.f,0.f,0.f); }
      }
    }
    if (t < TK){
      int node = base + t;
      ngv = (node < nNodes) ? batch[node] : -1;
    }
  };
  auto stageT = [&](int buf){
    #pragma unroll
    for (int q = 0; q < 4; ++q){
      bf16x8 o;
      if constexpr (BF) o = xv[q];
      else {
        float4 a = xf[q][0], c = xf[q][1];
        o[0]=f2bf(a.x); o[1]=f2bf(a.y); o[2]=f2bf(a.z); o[3]=f2bf(a.w);
        o[4]=f2bf(c.x); o[5]=f2bf(c.y); o[6]=f2bf(c.z); o[7]=f2bf(c.w);
      }
      *(bf16x8*)(&Ain[buf][srow + q*8][scol]) = o;
    }
    if (t < TK) ngS[buf][t] = ngv;
  };

  issueT(tile0);
  stageT(0);
  if (tile0 + 1 < tile1) issueT(tile0 + 1);

  int cur = 0;
  for (int tile = tile0; tile < tile1; ++tile, cur ^= 1){
    ldsbar();

    int gr[2][4];
    uint32_t hvp[2][4];
    #pragma unroll
    for (int r = 0; r < 2; ++r)
      #pragma unroll
      for (int j = 0; j < 4; ++j){
        int g = ngS[cur][r*16 + l4*4 + j];
        gr[r][j] = g;
        hvp[r][j] = (g >= 0) ? hgp[(size_t)g*128 + hgcol] : 0u;
      }

    f32x4 acc0[2], acc1[2];
    #pragma unroll
    for (int r = 0; r < 2; ++r){ acc0[r] = (f32x4){0.f,0.f,0.f,0.f}; acc1[r] = (f32x4){0.f,0.f,0.f,0.f}; }
    #pragma unroll
    for (int kc = 0; kc < 8; ++kc){
      #pragma unroll
      for (int r = 0; r < 2; ++r){
        bf16x8 a = *(bf16x8*)(&Ain[cur][r*16 + l15][kc*32 + l4*8]);
        acc0[r] = __builtin_amdgcn_mfma_f32_16x16x32_bf16(a, Bf0[kc], acc0[r], 0, 0, 0);
        acc1[r] = __builtin_amdgcn_mfma_f32_16x16x32_bf16(a, Bf1[kc], acc1[r], 0, 0, 0);
      }
    }

    if (tile + 1 < tile1){
      stageT(cur ^ 1);
      if (tile + 2 < tile1) issueT(tile + 2);
    }

    float p[2][4];
    #pragma unroll
    for (int r = 0; r < 2; ++r)
      #pragma unroll
      for (int j = 0; j < 4; ++j){
        float h0 = fmaxf(acc0[r][j] + bf2f((short)(uint16_t)(hvp[r][j] & 0xFFFFu)), 0.f);
        float h1 = fmaxf(acc1[r][j] + bf2f((short)(uint16_t)(hvp[r][j] >> 16)), 0.f);
        p[r][j] = w2v0*h0 + w2v1*h1;
      }
    #pragma unroll
    for (int off = 1; off < 16; off <<= 1){
      #pragma unroll
      for (int r = 0; r < 2; ++r)
        #pragma unroll
        for (int j = 0; j < 4; ++j) p[r][j] += __shfl_xor(p[r][j], off);
    }
    if (l15 == 0){
      int base = tile * TK;
      #pragma unroll
      for (int r = 0; r < 2; ++r)
        #pragma unroll
        for (int j = 0; j < 4; ++j){
          if (gr[r][j] >= 0)
            atomicAdd(&sgate[base + r*16 + l4*4 + j], p[r][j]);
        }
    }
  }
}

// ---------------- K1b: streaming weighted pooling (128-row tiles); zeroes sgate ----------------
template<bool BF>
__global__ __launch_bounds__(512) __attribute__((amdgpu_waves_per_eu(2, 8)))
void k1b_pool(
    const float* __restrict__ xf32, const short* __restrict__ xbf,
    const int* __restrict__ batch, float* __restrict__ sgate,
    const float* __restrict__ b2p, float* __restrict__ pool, int nNodes){

  __shared__ int   ng[TP0];
  __shared__ float gs[TP0];
  __shared__ float Pacc[8][H];
  __shared__ int   spanSh;

  const int t = threadIdx.x;
  const int base = blockIdx.x * TP0;
  const int c4 = (t & 63) * 4;
  const int r0 = (t >> 6) * 16;

  // issue all 16 x loads first
  ushort4 u[16];
  float4  vf[16];
  #pragma unroll
  for (int i = 0; i < 16; ++i){
    int node = base + r0 + i;
    if constexpr (BF){
      u[i] = (node < nNodes) ? *(const ushort4*)(xbf + (size_t)node*H + c4)
                             : make_ushort4(0,0,0,0);
    } else {
      vf[i] = (node < nNodes) ? *(const float4*)(xf32 + (size_t)node*H + c4)
                              : make_float4(0.f,0.f,0.f,0.f);
    }
  }

  const float b2v = b2p[0];
  if (t < TP0){
    int node = base + t;
    if (node < nNodes){
      ng[t] = batch[node];
      gs[t] = sigmoidf_(sgate[node] + b2v);
      sgate[node] = 0.f;                 // ready for next k1a pass
    } else { ng[t] = -1; gs[t] = 0.f; }
  }
  for (int w = t; w < 8*H; w += 512) ((float*)Pacc)[w] = 0.f;
  __syncthreads();

  if (t == 0){
    int lg = ng[0];
    if (base + TP0 <= nNodes) lg = ng[TP0-1];
    else { for (int i = TP0-1; i > 0; --i){ if (ng[i] >= 0){ lg = ng[i]; break; } } }
    spanSh = (ng[0] >= 0) ? (lg - ng[0]) : -1;
  }
  __syncthreads();

  const int g0 = ng[0];
  const bool useLds = (spanSh >= 0) && (spanSh < 8);

  float ax=0.f, ay=0.f, az=0.f, aw=0.f;
  int cur = ng[r0];
  if (cur >= 0){
    #pragma unroll
    for (int i = 0; i < 16; ++i){
      int g = ng[r0 + i];
      if (g < 0) break;
      if (g != cur){
        if (useLds){
          atomicAdd(&Pacc[cur-g0][c4], ax);   atomicAdd(&Pacc[cur-g0][c4+1], ay);
          atomicAdd(&Pacc[cur-g0][c4+2], az); atomicAdd(&Pacc[cur-g0][c4+3], aw);
        } else {
          atomicAdd(&pool[(size_t)cur*H + c4], ax);   atomicAdd(&pool[(size_t)cur*H + c4+1], ay);
          atomicAdd(&pool[(size_t)cur*H + c4+2], az); atomicAdd(&pool[(size_t)cur*H + c4+3], aw);
        }
        ax=ay=az=aw=0.f; cur = g;
      }
      float gv = gs[r0 + i];
      if constexpr (BF){
        ax += gv * bf2f((short)u[i].x); ay += gv * bf2f((short)u[i].y);
        az += gv * bf2f((short)u[i].z); aw += gv * bf2f((short)u[i].w);
      } else {
        ax += gv * bf2f(f2bf(vf[i].x)); ay += gv * bf2f(f2bf(vf[i].y));
        az += gv * bf2f(f2bf(vf[i].z)); aw += gv * bf2f(f2bf(vf[i].w));
      }
    }
    if (useLds){
      atomicAdd(&Pacc[cur-g0][c4], ax);   atomicAdd(&Pacc[cur-g0][c4+1], ay);
      atomicAdd(&Pacc[cur-g0][c4+2], az); atomicAdd(&Pacc[cur-g0][c4+3], aw);
    } else {
      atomicAdd(&pool[(size_t)cur*H + c4], ax);   atomicAdd(&pool[(size_t)cur*H + c4+1], ay);
      atomicAdd(&pool[(size_t)cur*H + c4+2], az); atomicAdd(&pool[(size_t)cur*H + c4+3], aw);
    }
  }
  __syncthreads();

  if (useLds){
    int nr = spanSh + 1;
    for (int w = t; w < nr*H; w += 512){
      int r = w >> 8, c = w & 255;
      float vv = Pacc[r][c];
      if (vv != 0.f) atomicAdd(&pool[(size_t)(g0+r)*H + c], vv);
    }
  }
}

// ---------------- K2: fused GRU (+ optional hgp for next ts); zeroes pool ----------------
__global__ __launch_bounds__(256) void k2_gru(float* __restrict__ pool,
    const float* __restrict__ counts, const float* __restrict__ repr_in,
    const short* __restrict__ wihbf, const short* __restrict__ whhbf,
    const float* __restrict__ bih, const float* __restrict__ bhh,
    float* __restrict__ repr_out,
    const short* __restrict__ w1bf, const float* __restrict__ b1,
    uint32_t* __restrict__ hgp, int doHg){

  __shared__ short Anew[16][H + 8];
  __shared__ short Aold[16][H + 8];
  __shared__ float hold[16][H];
  __shared__ float srz[16][2*H];
  __shared__ float sni[16][H];
  __shared__ float snh[16][H];

  const int t    = threadIdx.x;
  const int wid  = t >> 6;
  const int lane = t & 63;
  const int l15  = lane & 15;
  const int l4   = lane >> 4;
  const int g0   = blockIdx.x * 16;

  for (int u = t; u < 16*H; u += 256){
    int row = u >> 8, c = u & 255;
    int g = g0 + row;
    float cnt = fmaxf(counts[g], 1.f);
    float rin = repr_in[(size_t)g*H + c];
    float nr  = pool[(size_t)g*H + c] / cnt;
    pool[(size_t)g*H + c] = 0.f;           // ready for next pooling pass
    Anew[row][c] = f2bf(nr);
    Aold[row][c] = f2bf(rin);
    hold[row][c] = rin;
  }
  __syncthreads();

  f32x4 ai[12], ah[12];
  #pragma unroll
  for (int i = 0; i < 12; ++i){ ai[i] = (f32x4){0.f,0.f,0.f,0.f}; ah[i] = (f32x4){0.f,0.f,0.f,0.f}; }

  for (int kc = 0; kc < 8; ++kc){
    bf16x8 an = *(bf16x8*)(&Anew[l15][kc*32 + l4*8]);
    bf16x8 ao = *(bf16x8*)(&Aold[l15][kc*32 + l4*8]);
    #pragma unroll
    for (int nt = 0; nt < 12; ++nt){
      int n = wid*192 + nt*16 + l15;
      bf16x8 bi = *(const bf16x8*)(wihbf + (size_t)n*H + kc*32 + l4*8);
      bf16x8 bh = *(const bf16x8*)(whhbf + (size_t)n*H + kc*32 + l4*8);
      ai[nt] = __builtin_amdgcn_mfma_f32_16x16x32_bf16(an, bi, ai[nt], 0, 0, 0);
      ah[nt] = __builtin_amdgcn_mfma_f32_16x16x32_bf16(ao, bh, ah[nt], 0, 0, 0);
    }
  }

  #pragma unroll
  for (int nt = 0; nt < 12; ++nt){
    int n = wid*192 + nt*16 + l15;
    float bi = bih[n], bh = bhh[n];
    #pragma unroll
    for (int r = 0; r < 4; ++r){
      int row = l4*4 + r;
      float si = ai[nt][r] + bi;
      float sh = ah[nt][r] + bh;
      if (n < 2*H) srz[row][n] = si + sh;
      else { sni[row][n - 2*H] = si; snh[row][n - 2*H] = sh; }
    }
  }
  __syncthreads();

  for (int u = t; u < 16*H; u += 256){
    int row = u >> 8, c = u & 255;
    float rr = sigmoidf_(srz[row][c]);
    float zz = sigmoidf_(srz[row][H + c]);
    float nn = tanhf(sni[row][c] + rr * snh[row][c]);
    float hv = (1.f - zz) * nn + zz * hold[row][c];
    float out = fmaxf(hv, 0.f);
    repr_out[(size_t)(g0 + row)*H + c] = out;
    Anew[row][c] = f2bf(out);              // staged for fused hg
  }

  if (doHg){
    __syncthreads();
    f32x4 acc[4];
    #pragma unroll
    for (int i = 0; i < 4; ++i) acc[i] = (f32x4){0.f,0.f,0.f,0.f};
    #pragma unroll
    for (int kc = 0; kc < 8; ++kc){
      bf16x8 a = *(bf16x8*)(&Anew[l15][kc*32 + l4*8]);
      #pragma unroll
      for (int nt = 0; nt < 4; ++nt){
        int col = wid*64 + nt*16 + l15;
        bf16x8 b = *(const bf16x8*)(w1bf + (size_t)col*H + kc*32 + l4*8);
        acc[nt] = __builtin_amdgcn_mfma_f32_16x16x32_bf16(a, b, acc[nt], 0, 0, 0);
      }
    }
    const float b1v0 = b1[wid*64 + l15];
    const float b1v1 = b1[wid*64 + 16 + l15];
    const float b1v2 = b1[wid*64 + 32 + l15];
    const float b1v3 = b1[wid*64 + 48 + l15];
    #pragma unroll
    for (int j = 0; j < 4; ++j){
      int row = l4*4 + j;
      hgp[(size_t)(g0+row)*128 + wid*32 + l15]      = pk2(acc[0][j]+b1v0, acc[1][j]+b1v1);
      hgp[(size_t)(g0+row)*128 + wid*32 + 16 + l15] = pk2(acc[2][j]+b1v2, acc[3][j]+b1v3);
    }
  }
}

extern "C" void kernel_launch(void* const* d_in, const int* in_sizes, int n_in,
                              void* d_out, int out_size, void* d_ws, size_t ws_size,
                              hipStream_t stream){
  const float* x    = (const float*)d_in[0];
  const float* w1   = (const float*)d_in[1];
  const float* b1   = (const float*)d_in[2];
  const float* w2   = (const float*)d_in[3];
  const float* b2   = (const float*)d_in[4];
  const float* wih  = (const float*)d_in[5];
  const float* whh  = (const float*)d_in[6];
  const float* bih  = (const float*)d_in[7];
  const float* bhh  = (const float*)d_in[8];
  const int*   batch= (const int*)d_in[9];
  const int N = in_sizes[9];

  char* ws = (char*)d_ws;
  short* w1bf   = (short*)(ws + 0);            // 128 KB
  short* wihbf  = (short*)(ws + (1u<<17));     // 384 KB @128K
  short* whhbf  = (short*)(ws + (1u<<19));     // 384 KB @512K
  float* counts = (float*)(ws + 917504);       // 16 KB @896K
  float* pool   = (float*)(ws + (1u<<20));     // 4 MB @1M
  float* repr   = (float*)(ws + (1u<<20) + (1u<<22)); // 4 MB @5M
  float* sgate  = (float*)(ws + (9u<<20));     // 2 MB @9M
  uint32_t* hgp = (uint32_t*)(ws + (12u<<20)); // 2 MB @12M
  float* outp   = (float*)d_out;

  const size_t XBF_OFF = (size_t)16u << 20;    // 16 MB
  const bool useXbf = ws_size >= XBF_OFF + (size_t)N * H * sizeof(short);
  short* xbf = useXbf ? (short*)(ws + XBF_OFF) : nullptr;

  const int nTiles  = (N + TK - 1) / TK;       // 15625
  const int nChains = 512;
  const int nBlk1a  = nChains * 2;             // 1024 blocks = 4/CU resident
  const int nBlkP   = (N + TP0 - 1) / TP0;     // 3907

  conv_w<<<768, 256, 0, stream>>>(w1, wih, whh, w1bf, wihbf, whhbf, counts, pool);
  k0_pool<<<nBlkP, 512, 0, stream>>>(x, batch, pool, counts, xbf, sgate, N);
  k0b_div<<<G*H/256, 256, 0, stream>>>(pool, counts, repr, pool);
  kT_hg<<<G/16, 256, 0, stream>>>(repr, w1bf, b1, hgp);

  for (int ts = 0; ts < 2; ++ts){
    if (useXbf){
      k1a_gate<true><<<nBlk1a, 256, 0, stream>>>(x, xbf, batch, hgp, w1bf, w2, sgate, N, nTiles, nChains);
      k1b_pool<true><<<nBlkP, 512, 0, stream>>>(x, xbf, batch, sgate, b2, pool, N);
    } else {
      k1a_gate<false><<<nBlk1a, 256, 0, stream>>>(x, xbf, batch, hgp, w1bf, w2, sgate, N, nTiles, nChains);
      k1b_pool<false><<<nBlkP, 512, 0, stream>>>(x, xbf, batch, sgate, b2, pool, N);
    }
    k2_gru<<<G/16, 256, 0, stream>>>(pool, counts, repr, wihbf, whhbf, bih, bhh,
                                     (ts == 0) ? repr : outp,
                                     w1bf, b1, hgp, (ts == 0) ? 1 : 0);
  }
}

// Round 14
// 699.032 us; speedup vs baseline: 1.3156x; 1.0681x over previous
//
#include <hip/hip_runtime.h>
#include <hip/hip_bf16.h>
#include <stdint.h>

#define H 256
#define G 4096
#define TK 32     // k1a tile rows
#define TP0 128   // k0/k1b tile rows

typedef __attribute__((ext_vector_type(8))) short bf16x8;
typedef __attribute__((ext_vector_type(4))) float f32x4;

__device__ inline short f2bf(float f){
  union { float f; uint32_t u; } v; v.f = f;
  uint32_t r = (v.u + 0x7FFFu + ((v.u >> 16) & 1u)) >> 16;
  return (short)(uint16_t)r;
}
__device__ inline float bf2f(short s){
  union { float f; uint32_t u; } v; v.u = ((uint32_t)(uint16_t)s) << 16;
  return v.f;
}
__device__ inline uint32_t pk2(float lo, float hi){
  return (uint32_t)(uint16_t)f2bf(lo) | ((uint32_t)(uint16_t)f2bf(hi) << 16);
}
__device__ inline uint32_t pkfp8(float4 v){
  int u = __builtin_amdgcn_cvt_pk_fp8_f32(v.x, v.y, 0, false);
  u = __builtin_amdgcn_cvt_pk_fp8_f32(v.z, v.w, u, true);
  return (uint32_t)u;
}
__device__ inline float sigmoidf_(float x){ return 1.f / (1.f + __expf(-x)); }

// LDS-only barrier: does NOT drain vmcnt, so in-flight global loads continue.
__device__ inline void ldsbar(){
  asm volatile("s_waitcnt lgkmcnt(0)" ::: "memory");
  __builtin_amdgcn_s_barrier();
}

// ---------------- conv_w: weight conversions + zero counts/pool ----------------
__global__ void conv_w(const float* __restrict__ w1, const float* __restrict__ wih,
                       const float* __restrict__ whh,
                       short* __restrict__ o1, short* __restrict__ oih, short* __restrict__ ohh,
                       uint8_t* __restrict__ w1q,
                       float* __restrict__ counts, float* __restrict__ pool){
  int i = blockIdx.x * 256 + threadIdx.x;
  if (i < H*H) o1[i] = f2bf(w1[i]);
  if (i < 3*H*H){ oih[i] = f2bf(wih[i]); ohh[i] = f2bf(whh[i]); }
  if (i < H*H/4){
    float4 v = *(const float4*)(w1 + (size_t)i*4);
    *(uint32_t*)(w1q + (size_t)i*4) = pkfp8(v);
  }
  if (i < G) counts[i] = 0.f;
  for (int j = i; j < G*H; j += 768*256) pool[j] = 0.f;
}

// ---------------- K0: mean-pool + counts + write x_bf16 + x_fp8 + zero sgate ----------------
__global__ __launch_bounds__(512) __attribute__((amdgpu_waves_per_eu(2, 8)))
void k0_pool(const float* __restrict__ x, const int* __restrict__ batch,
             float* __restrict__ pool, float* __restrict__ counts,
             short* __restrict__ xbf, uint8_t* __restrict__ xq,
             float* __restrict__ sgate, int nNodes){
  __shared__ int   ng[TP0];
  __shared__ float Pacc[8][H];
  __shared__ float Cacc[8];
  __shared__ int   spanSh;

  const int t = threadIdx.x;
  const int base = blockIdx.x * TP0;
  const int c4 = (t & 63) * 4;
  const int r0 = (t >> 6) * 16;   // 8 row-groups of 16 rows

  // issue ALL 16 loads first: 256 B/thread in flight -> ILP-covered latency
  float4 v[16];
  #pragma unroll
  for (int i = 0; i < 16; ++i){
    int node = base + r0 + i;
    if (node < nNodes) v[i] = *(const float4*)(x + (size_t)node*H + c4);
    else v[i] = make_float4(0.f,0.f,0.f,0.f);
  }

  { int gi = blockIdx.x * 512 + t; if (gi < nNodes) sgate[gi] = 0.f; }

  if (t < TP0) ng[t] = (base + t < nNodes) ? batch[base + t] : -1;
  for (int u = t; u < 8*H; u += 512) ((float*)Pacc)[u] = 0.f;
  if (t < 8) Cacc[t] = 0.f;
  __syncthreads();

  if (t == 0){
    int lg = ng[0];
    if (base + TP0 <= nNodes) lg = ng[TP0-1];
    else { for (int i = TP0-1; i > 0; --i){ if (ng[i] >= 0){ lg = ng[i]; break; } } }
    spanSh = (ng[0] >= 0) ? (lg - ng[0]) : -1;
  }

  if (xbf){
    #pragma unroll
    for (int i = 0; i < 16; ++i){
      int node = base + r0 + i;
      if (node < nNodes){
        ushort4 o;
        o.x = (uint16_t)f2bf(v[i].x); o.y = (uint16_t)f2bf(v[i].y);
        o.z = (uint16_t)f2bf(v[i].z); o.w = (uint16_t)f2bf(v[i].w);
        *(ushort4*)(xbf + (size_t)node*H + c4) = o;
        *(uint32_t*)(xq + (size_t)node*H + c4) = pkfp8(v[i]);
      }
    }
  }
  __syncthreads();

  const int g0 = ng[0];
  const bool useLds = (spanSh >= 0) && (spanSh < 8);

  float ax=0.f, ay=0.f, az=0.f, aw=0.f;
  int cur = ng[r0];
  if (cur >= 0){
    #pragma unroll
    for (int i = 0; i < 16; ++i){
      int g = ng[r0 + i];
      if (g < 0) break;
      if (g != cur){
        if (useLds){
          atomicAdd(&Pacc[cur-g0][c4], ax);   atomicAdd(&Pacc[cur-g0][c4+1], ay);
          atomicAdd(&Pacc[cur-g0][c4+2], az); atomicAdd(&Pacc[cur-g0][c4+3], aw);
        } else {
          atomicAdd(&pool[(size_t)cur*H + c4], ax);   atomicAdd(&pool[(size_t)cur*H + c4+1], ay);
          atomicAdd(&pool[(size_t)cur*H + c4+2], az); atomicAdd(&pool[(size_t)cur*H + c4+3], aw);
        }
        ax=ay=az=aw=0.f; cur = g;
      }
      ax += v[i].x; ay += v[i].y; az += v[i].z; aw += v[i].w;
    }
    if (useLds){
      atomicAdd(&Pacc[cur-g0][c4], ax);   atomicAdd(&Pacc[cur-g0][c4+1], ay);
      atomicAdd(&Pacc[cur-g0][c4+2], az); atomicAdd(&Pacc[cur-g0][c4+3], aw);
    } else {
      atomicAdd(&pool[(size_t)cur*H + c4], ax);   atomicAdd(&pool[(size_t)cur*H + c4+1], ay);
      atomicAdd(&pool[(size_t)cur*H + c4+2], az); atomicAdd(&pool[(size_t)cur*H + c4+3], aw);
    }
  }
  if (t < TP0 && ng[t] >= 0){
    if (useLds) atomicAdd(&Cacc[ng[t]-g0], 1.f);
    else        atomicAdd(&counts[ng[t]], 1.f);
  }
  __syncthreads();

  if (useLds){
    int nr = spanSh + 1;
    for (int u = t; u < nr*H; u += 512){
      int r = u >> 8, c = u & 255;
      float vv = Pacc[r][c];
      if (vv != 0.f) atomicAdd(&pool[(size_t)(g0+r)*H + c], vv);
    }
    if (t < nr && Cacc[t] != 0.f) atomicAdd(&counts[g0 + t], Cacc[t]);
  }
}

// ---------------- K0b: repr = pool / max(counts,1) ; zeroes pool ----------------
__global__ void k0b_div(const float* __restrict__ pool, const float* __restrict__ counts,
                        float* __restrict__ repr, float* __restrict__ pool_mut){
  size_t i = (size_t)blockIdx.x * 256 + threadIdx.x;
  int g = (int)(i >> 8);
  repr[i] = pool[i] / fmaxf(counts[g], 1.f);
  pool_mut[i] = 0.f;
}

// ---------------- KT: hgp[g] = packed bf16 pairs of W1*bf16(repr[g]) + b1 ----------------
__global__ __launch_bounds__(256) void kT_hg(const float* __restrict__ repr,
    const short* __restrict__ w1bf, const float* __restrict__ b1,
    uint32_t* __restrict__ hgp){
  __shared__ short Ar[16][H + 8];
  const int t    = threadIdx.x;
  const int wid  = t >> 6;
  const int lane = t & 63;
  const int l15  = lane & 15;
  const int l4   = lane >> 4;
  const int g0   = blockIdx.x * 16;

  for (int u = t; u < 16*32; u += 256){
    int row = u >> 5, cg = u & 31;
    int c0 = cg * 8;
    const float4* rp = (const float4*)(repr + (size_t)(g0+row)*H + c0);
    float4 r0 = rp[0], r1 = rp[1];
    bf16x8 o;
    o[0]=f2bf(r0.x); o[1]=f2bf(r0.y); o[2]=f2bf(r0.z); o[3]=f2bf(r0.w);
    o[4]=f2bf(r1.x); o[5]=f2bf(r1.y); o[6]=f2bf(r1.z); o[7]=f2bf(r1.w);
    *(bf16x8*)(&Ar[row][c0]) = o;
  }
  __syncthreads();

  f32x4 acc[4];
  #pragma unroll
  for (int i = 0; i < 4; ++i) acc[i] = (f32x4){0.f,0.f,0.f,0.f};
  #pragma unroll
  for (int kc = 0; kc < 8; ++kc){
    bf16x8 a = *(bf16x8*)(&Ar[l15][kc*32 + l4*8]);
    #pragma unroll
    for (int nt = 0; nt < 4; ++nt){
      int col = wid*64 + nt*16 + l15;
      bf16x8 b = *(const bf16x8*)(w1bf + (size_t)col*H + kc*32 + l4*8);
      acc[nt] = __builtin_amdgcn_mfma_f32_16x16x32_bf16(a, b, acc[nt], 0, 0, 0);
    }
  }
  const float b1v0 = b1[wid*64 + l15];
  const float b1v1 = b1[wid*64 + 16 + l15];
  const float b1v2 = b1[wid*64 + 32 + l15];
  const float b1v3 = b1[wid*64 + 48 + l15];
  #pragma unroll
  for (int j = 0; j < 4; ++j){
    int row = l4*4 + j;
    hgp[(size_t)(g0+row)*128 + wid*32 + l15]      = pk2(acc[0][j]+b1v0, acc[1][j]+b1v1);
    hgp[(size_t)(g0+row)*128 + wid*32 + 16 + l15] = pk2(acc[2][j]+b1v2, acc[3][j]+b1v3);
  }
}

// ---------------- K1a-fp8: gate scores, col-split persistent GEMM ----------------
// fp8 e4m3 x and W1 halve VGPR/LDS/bytes -> 5 chains/CU.
__global__ __launch_bounds__(256) __attribute__((amdgpu_waves_per_eu(4, 6)))
void k1a_fp8(
    const uint8_t* __restrict__ xq, const int* __restrict__ batch,
    const uint32_t* __restrict__ hgp, const uint8_t* __restrict__ w1q,
    const float* __restrict__ w2, float* __restrict__ sgate,
    int nNodes, int nTiles, int nChains){

  __shared__ uint8_t Ain[2][TK][H + 16];   // 272B pitch, 17.4 KB
  __shared__ int     ngS[2][TK];

  const int t    = threadIdx.x;
  const int wid  = t >> 6;      // 0..3
  const int lane = t & 63;
  const int l15  = lane & 15;
  const int l4   = lane >> 4;

  const int ch    = blockIdx.x >= nChains;
  const int chain = ch ? blockIdx.x - nChains : blockIdx.x;
  const int colB  = ch*128 + wid*32;
  const int hgcol = ch*64 + wid*16 + l15;   // packed-pair column index

  const int tile0 = (int)(((long long)chain * nTiles) / nChains);
  const int tile1 = (int)(((long long)(chain+1) * nTiles) / nChains);
  if (tile0 >= tile1) return;

  // W1 fp8 fragments: 32 VGPR
  long Bf0[8], Bf1[8];
  {
    const uint8_t* wp0 = w1q + (size_t)(colB + l15)*H + l4*8;
    #pragma unroll
    for (int kc = 0; kc < 8; ++kc){
      Bf0[kc] = *(const long*)(wp0 + kc*32);
      Bf1[kc] = *(const long*)(wp0 + 16*H + kc*32);
    }
  }
  const float w2v0 = w2[colB + l15];
  const float w2v1 = w2[colB + 16 + l15];

  const int srow  = t >> 4;        // 0..15
  const int scolB = (t & 15) * 16; // byte offset
  uint4 xv0, xv1;
  int ngv = -1;

  auto issueT = [&](int tile){
    int base = tile * TK;
    int n0 = base + srow, n1 = n0 + 16;
    xv0 = (n0 < nNodes) ? *(const uint4*)(xq + (size_t)n0*H + scolB) : make_uint4(0,0,0,0);
    xv1 = (n1 < nNodes) ? *(const uint4*)(xq + (size_t)n1*H + scolB) : make_uint4(0,0,0,0);
    if (t < TK){
      int node = base + t;
      ngv = (node < nNodes) ? batch[node] : -1;
    }
  };
  auto stageT = [&](int buf){
    *(uint4*)(&Ain[buf][srow][scolB])      = xv0;
    *(uint4*)(&Ain[buf][srow + 16][scolB]) = xv1;
    if (t < TK) ngS[buf][t] = ngv;
  };

  issueT(tile0);
  stageT(0);
  if (tile0 + 1 < tile1) issueT(tile0 + 1);

  int cur = 0;
  for (int tile = tile0; tile < tile1; ++tile, cur ^= 1){
    ldsbar();

    int gr[2][4];
    uint32_t hvp[2][4];
    #pragma unroll
    for (int r = 0; r < 2; ++r)
      #pragma unroll
      for (int j = 0; j < 4; ++j){
        int g = ngS[cur][r*16 + l4*4 + j];
        gr[r][j] = g;
        hvp[r][j] = (g >= 0) ? hgp[(size_t)g*128 + hgcol] : 0u;
      }

    f32x4 acc0[2], acc1[2];
    #pragma unroll
    for (int r = 0; r < 2; ++r){ acc0[r] = (f32x4){0.f,0.f,0.f,0.f}; acc1[r] = (f32x4){0.f,0.f,0.f,0.f}; }
    #pragma unroll
    for (int kc = 0; kc < 8; ++kc){
      #pragma unroll
      for (int r = 0; r < 2; ++r){
        long a = *(const long*)(&Ain[cur][r*16 + l15][kc*32 + l4*8]);
        acc0[r] = __builtin_amdgcn_mfma_f32_16x16x32_fp8_fp8(a, Bf0[kc], acc0[r], 0, 0, 0);
        acc1[r] = __builtin_amdgcn_mfma_f32_16x16x32_fp8_fp8(a, Bf1[kc], acc1[r], 0, 0, 0);
      }
    }

    if (tile + 1 < tile1){
      stageT(cur ^ 1);
      if (tile + 2 < tile1) issueT(tile + 2);
    }

    float p[2][4];
    #pragma unroll
    for (int r = 0; r < 2; ++r)
      #pragma unroll
      for (int j = 0; j < 4; ++j){
        float h0 = fmaxf(acc0[r][j] + bf2f((short)(uint16_t)(hvp[r][j] & 0xFFFFu)), 0.f);
        float h1 = fmaxf(acc1[r][j] + bf2f((short)(uint16_t)(hvp[r][j] >> 16)), 0.f);
        p[r][j] = w2v0*h0 + w2v1*h1;
      }
    #pragma unroll
    for (int off = 1; off < 16; off <<= 1){
      #pragma unroll
      for (int r = 0; r < 2; ++r)
        #pragma unroll
        for (int j = 0; j < 4; ++j) p[r][j] += __shfl_xor(p[r][j], off);
    }
    if (l15 == 0){
      int base = tile * TK;
      #pragma unroll
      for (int r = 0; r < 2; ++r)
        #pragma unroll
        for (int j = 0; j < 4; ++j){
          if (gr[r][j] >= 0)
            atomicAdd(&sgate[base + r*16 + l4*4 + j], p[r][j]);
        }
    }
  }
}

// ---------------- K1b: streaming weighted pooling (128-row tiles); zeroes sgate ----------------
template<bool BF>
__global__ __launch_bounds__(512) __attribute__((amdgpu_waves_per_eu(2, 8)))
void k1b_pool(
    const float* __restrict__ xf32, const short* __restrict__ xbf,
    const int* __restrict__ batch, float* __restrict__ sgate,
    const float* __restrict__ b2p, float* __restrict__ pool, int nNodes){

  __shared__ int   ng[TP0];
  __shared__ float gs[TP0];
  __shared__ float Pacc[8][H];
  __shared__ int   spanSh;

  const int t = threadIdx.x;
  const int base = blockIdx.x * TP0;
  const int c4 = (t & 63) * 4;
  const int r0 = (t >> 6) * 16;

  ushort4 u[16];
  float4  vf[16];
  #pragma unroll
  for (int i = 0; i < 16; ++i){
    int node = base + r0 + i;
    if constexpr (BF){
      u[i] = (node < nNodes) ? *(const ushort4*)(xbf + (size_t)node*H + c4)
                             : make_ushort4(0,0,0,0);
    } else {
      vf[i] = (node < nNodes) ? *(const float4*)(xf32 + (size_t)node*H + c4)
                              : make_float4(0.f,0.f,0.f,0.f);
    }
  }

  const float b2v = b2p[0];
  if (t < TP0){
    int node = base + t;
    if (node < nNodes){
      ng[t] = batch[node];
      gs[t] = sigmoidf_(sgate[node] + b2v);
      sgate[node] = 0.f;                 // ready for next k1a pass
    } else { ng[t] = -1; gs[t] = 0.f; }
  }
  for (int w = t; w < 8*H; w += 512) ((float*)Pacc)[w] = 0.f;
  __syncthreads();

  if (t == 0){
    int lg = ng[0];
    if (base + TP0 <= nNodes) lg = ng[TP0-1];
    else { for (int i = TP0-1; i > 0; --i){ if (ng[i] >= 0){ lg = ng[i]; break; } } }
    spanSh = (ng[0] >= 0) ? (lg - ng[0]) : -1;
  }
  __syncthreads();

  const int g0 = ng[0];
  const bool useLds = (spanSh >= 0) && (spanSh < 8);

  float ax=0.f, ay=0.f, az=0.f, aw=0.f;
  int cur = ng[r0];
  if (cur >= 0){
    #pragma unroll
    for (int i = 0; i < 16; ++i){
      int g = ng[r0 + i];
      if (g < 0) break;
      if (g != cur){
        if (useLds){
          atomicAdd(&Pacc[cur-g0][c4], ax);   atomicAdd(&Pacc[cur-g0][c4+1], ay);
          atomicAdd(&Pacc[cur-g0][c4+2], az); atomicAdd(&Pacc[cur-g0][c4+3], aw);
        } else {
          atomicAdd(&pool[(size_t)cur*H + c4], ax);   atomicAdd(&pool[(size_t)cur*H + c4+1], ay);
          atomicAdd(&pool[(size_t)cur*H + c4+2], az); atomicAdd(&pool[(size_t)cur*H + c4+3], aw);
        }
        ax=ay=az=aw=0.f; cur = g;
      }
      float gv = gs[r0 + i];
      if constexpr (BF){
        ax += gv * bf2f((short)u[i].x); ay += gv * bf2f((short)u[i].y);
        az += gv * bf2f((short)u[i].z); aw += gv * bf2f((short)u[i].w);
      } else {
        ax += gv * bf2f(f2bf(vf[i].x)); ay += gv * bf2f(f2bf(vf[i].y));
        az += gv * bf2f(f2bf(vf[i].z)); aw += gv * bf2f(f2bf(vf[i].w));
      }
    }
    if (useLds){
      atomicAdd(&Pacc[cur-g0][c4], ax);   atomicAdd(&Pacc[cur-g0][c4+1], ay);
      atomicAdd(&Pacc[cur-g0][c4+2], az); atomicAdd(&Pacc[cur-g0][c4+3], aw);
    } else {
      atomicAdd(&pool[(size_t)cur*H + c4], ax);   atomicAdd(&pool[(size_t)cur*H + c4+1], ay);
      atomicAdd(&pool[(size_t)cur*H + c4+2], az); atomicAdd(&pool[(size_t)cur*H + c4+3], aw);
    }
  }
  __syncthreads();

  if (useLds){
    int nr = spanSh + 1;
    for (int w = t; w < nr*H; w += 512){
      int r = w >> 8, c = w & 255;
      float vv = Pacc[r][c];
      if (vv != 0.f) atomicAdd(&pool[(size_t)(g0+r)*H + c], vv);
    }
  }
}

// ---------------- legacy bf16 k1a (fallback when ws too small for xq) ----------------
__global__ __launch_bounds__(256) __attribute__((amdgpu_waves_per_eu(3, 4)))
void k1a_gate_f32(
    const float* __restrict__ xf32, const int* __restrict__ batch,
    const uint32_t* __restrict__ hgp, const short* __restrict__ w1bf,
    const float* __restrict__ w2, float* __restrict__ sgate,
    int nNodes, int nTiles, int nChains){

  __shared__ short Ain[2][TK][H + 8];
  __shared__ int   ngS[2][TK];

  const int t    = threadIdx.x;
  const int wid  = t >> 6;
  const int lane = t & 63;
  const int l15  = lane & 15;
  const int l4   = lane >> 4;

  const int ch    = blockIdx.x >= nChains;
  const int chain = ch ? blockIdx.x - nChains : blockIdx.x;
  const int colB  = ch*128 + wid*32;
  const int hgcol = ch*64 + wid*16 + l15;

  const int tile0 = (int)(((long long)chain * nTiles) / nChains);
  const int tile1 = (int)(((long long)(chain+1) * nTiles) / nChains);
  if (tile0 >= tile1) return;

  bf16x8 Bf0[8], Bf1[8];
  {
    const short* wp0 = w1bf + (size_t)(colB + l15)*H + l4*8;
    #pragma unroll
    for (int kc = 0; kc < 8; ++kc){
      Bf0[kc] = *(const bf16x8*)(wp0 + kc*32);
      Bf1[kc] = *(const bf16x8*)(wp0 + 16*H + kc*32);
    }
  }
  const float w2v0 = w2[colB + l15];
  const float w2v1 = w2[colB + 16 + l15];

  const int srow = t >> 5;
  const int scol = (t & 31) * 8;
  float4 xf[4][2];
  int ngv = -1;

  auto issueT = [&](int tile){
    int base = tile * TK;
    #pragma unroll
    for (int q = 0; q < 4; ++q){
      int node = base + srow + q*8;
      if (node < nNodes){
        const float4* xp = (const float4*)(xf32 + (size_t)node*H + scol);
        xf[q][0] = xp[0]; xf[q][1] = xp[1];
      } else { xf[q][0] = make_float4(0.f,0.f,0.f,0.f); xf[q][1] = make_float4(0.f,0.f,0.f,0.f); }
    }
    if (t < TK){
      int node = base + t;
      ngv = (node < nNodes) ? batch[node] : -1;
    }
  };
  auto stageT = [&](int buf){
    #pragma unroll
    for (int q = 0; q < 4; ++q){
      bf16x8 o;
      float4 a = xf[q][0], c = xf[q][1];
      o[0]=f2bf(a.x); o[1]=f2bf(a.y); o[2]=f2bf(a.z); o[3]=f2bf(a.w);
      o[4]=f2bf(c.x); o[5]=f2bf(c.y); o[6]=f2bf(c.z); o[7]=f2bf(c.w);
      *(bf16x8*)(&Ain[buf][srow + q*8][scol]) = o;
    }
    if (t < TK) ngS[buf][t] = ngv;
  };

  issueT(tile0);
  stageT(0);
  if (tile0 + 1 < tile1) issueT(tile0 + 1);

  int cur = 0;
  for (int tile = tile0; tile < tile1; ++tile, cur ^= 1){
    ldsbar();

    int gr[2][4];
    uint32_t hvp[2][4];
    #pragma unroll
    for (int r = 0; r < 2; ++r)
      #pragma unroll
      for (int j = 0; j < 4; ++j){
        int g = ngS[cur][r*16 + l4*4 + j];
        gr[r][j] = g;
        hvp[r][j] = (g >= 0) ? hgp[(size_t)g*128 + hgcol] : 0u;
      }

    f32x4 acc0[2], acc1[2];
    #pragma unroll
    for (int r = 0; r < 2; ++r){ acc0[r] = (f32x4){0.f,0.f,0.f,0.f}; acc1[r] = (f32x4){0.f,0.f,0.f,0.f}; }
    #pragma unroll
    for (int kc = 0; kc < 8; ++kc){
      #pragma unroll
      for (int r = 0; r < 2; ++r){
        bf16x8 a = *(bf16x8*)(&Ain[cur][r*16 + l15][kc*32 + l4*8]);
        acc0[r] = __builtin_amdgcn_mfma_f32_16x16x32_bf16(a, Bf0[kc], acc0[r], 0, 0, 0);
        acc1[r] = __builtin_amdgcn_mfma_f32_16x16x32_bf16(a, Bf1[kc], acc1[r], 0, 0, 0);
      }
    }

    if (tile + 1 < tile1){
      stageT(cur ^ 1);
      if (tile + 2 < tile1) issueT(tile + 2);
    }

    float p[2][4];
    #pragma unroll
    for (int r = 0; r < 2; ++r)
      #pragma unroll
      for (int j = 0; j < 4; ++j){
        float h0 = fmaxf(acc0[r][j] + bf2f((short)(uint16_t)(hvp[r][j] & 0xFFFFu)), 0.f);
        float h1 = fmaxf(acc1[r][j] + bf2f((short)(uint16_t)(hvp[r][j] >> 16)), 0.f);
        p[r][j] = w2v0*h0 + w2v1*h1;
      }
    #pragma unroll
    for (int off = 1; off < 16; off <<= 1){
      #pragma unroll
      for (int r = 0; r < 2; ++r)
        #pragma unroll
        for (int j = 0; j < 4; ++j) p[r][j] += __shfl_xor(p[r][j], off);
    }
    if (l15 == 0){
      int base = tile * TK;
      #pragma unroll
      for (int r = 0; r < 2; ++r)
        #pragma unroll
        for (int j = 0; j < 4; ++j){
          if (gr[r][j] >= 0)
            atomicAdd(&sgate[base + r*16 + l4*4 + j], p[r][j]);
        }
    }
  }
}

// ---------------- K2: fused GRU (+ optional hgp for next ts); zeroes pool ----------------
__global__ __launch_bounds__(256) void k2_gru(float* __restrict__ pool,
    const float* __restrict__ counts, const float* __restrict__ repr_in,
    const short* __restrict__ wihbf, const short* __restrict__ whhbf,
    const float* __restrict__ bih, const float* __restrict__ bhh,
    float* __restrict__ repr_out,
    const short* __restrict__ w1bf, const float* __restrict__ b1,
    uint32_t* __restrict__ hgp, int doHg){

  __shared__ short Anew[16][H + 8];
  __shared__ short Aold[16][H + 8];
  __shared__ float hold[16][H];
  __shared__ float srz[16][2*H];
  __shared__ float sni[16][H];
  __shared__ float snh[16][H];

  const int t    = threadIdx.x;
  const int wid  = t >> 6;
  const int lane = t & 63;
  const int l15  = lane & 15;
  const int l4   = lane >> 4;
  const int g0   = blockIdx.x * 16;

  for (int u = t; u < 16*H; u += 256){
    int row = u >> 8, c = u & 255;
    int g = g0 + row;
    float cnt = fmaxf(counts[g], 1.f);
    float rin = repr_in[(size_t)g*H + c];
    float nr  = pool[(size_t)g*H + c] / cnt;
    pool[(size_t)g*H + c] = 0.f;
    Anew[row][c] = f2bf(nr);
    Aold[row][c] = f2bf(rin);
    hold[row][c] = rin;
  }
  __syncthreads();

  f32x4 ai[12], ah[12];
  #pragma unroll
  for (int i = 0; i < 12; ++i){ ai[i] = (f32x4){0.f,0.f,0.f,0.f}; ah[i] = (f32x4){0.f,0.f,0.f,0.f}; }

  for (int kc = 0; kc < 8; ++kc){
    bf16x8 an = *(bf16x8*)(&Anew[l15][kc*32 + l4*8]);
    bf16x8 ao = *(bf16x8*)(&Aold[l15][kc*32 + l4*8]);
    #pragma unroll
    for (int nt = 0; nt < 12; ++nt){
      int n = wid*192 + nt*16 + l15;
      bf16x8 bi = *(const bf16x8*)(wihbf + (size_t)n*H + kc*32 + l4*8);
      bf16x8 bh = *(const bf16x8*)(whhbf + (size_t)n*H + kc*32 + l4*8);
      ai[nt] = __builtin_amdgcn_mfma_f32_16x16x32_bf16(an, bi, ai[nt], 0, 0, 0);
      ah[nt] = __builtin_amdgcn_mfma_f32_16x16x32_bf16(ao, bh, ah[nt], 0, 0, 0);
    }
  }

  #pragma unroll
  for (int nt = 0; nt < 12; ++nt){
    int n = wid*192 + nt*16 + l15;
    float bi = bih[n], bh = bhh[n];
    #pragma unroll
    for (int r = 0; r < 4; ++r){
      int row = l4*4 + r;
      float si = ai[nt][r] + bi;
      float sh = ah[nt][r] + bh;
      if (n < 2*H) srz[row][n] = si + sh;
      else { sni[row][n - 2*H] = si; snh[row][n - 2*H] = sh; }
    }
  }
  __syncthreads();

  for (int u = t; u < 16*H; u += 256){
    int row = u >> 8, c = u & 255;
    float rr = sigmoidf_(srz[row][c]);
    float zz = sigmoidf_(srz[row][H + c]);
    float nn = tanhf(sni[row][c] + rr * snh[row][c]);
    float hv = (1.f - zz) * nn + zz * hold[row][c];
    float out = fmaxf(hv, 0.f);
    repr_out[(size_t)(g0 + row)*H + c] = out;
    Anew[row][c] = f2bf(out);
  }

  if (doHg){
    __syncthreads();
    f32x4 acc[4];
    #pragma unroll
    for (int i = 0; i < 4; ++i) acc[i] = (f32x4){0.f,0.f,0.f,0.f};
    #pragma unroll
    for (int kc = 0; kc < 8; ++kc){
      bf16x8 a = *(bf16x8*)(&Anew[l15][kc*32 + l4*8]);
      #pragma unroll
      for (int nt = 0; nt < 4; ++nt){
        int col = wid*64 + nt*16 + l15;
        bf16x8 b = *(const bf16x8*)(w1bf + (size_t)col*H + kc*32 + l4*8);
        acc[nt] = __builtin_amdgcn_mfma_f32_16x16x32_bf16(a, b, acc[nt], 0, 0, 0);
      }
    }
    const float b1v0 = b1[wid*64 + l15];
    const float b1v1 = b1[wid*64 + 16 + l15];
    const float b1v2 = b1[wid*64 + 32 + l15];
    const float b1v3 = b1[wid*64 + 48 + l15];
    #pragma unroll
    for (int j = 0; j < 4; ++j){
      int row = l4*4 + j;
      hgp[(size_t)(g0+row)*128 + wid*32 + l15]      = pk2(acc[0][j]+b1v0, acc[1][j]+b1v1);
      hgp[(size_t)(g0+row)*128 + wid*32 + 16 + l15] = pk2(acc[2][j]+b1v2, acc[3][j]+b1v3);
    }
  }
}

extern "C" void kernel_launch(void* const* d_in, const int* in_sizes, int n_in,
                              void* d_out, int out_size, void* d_ws, size_t ws_size,
                              hipStream_t stream){
  const float* x    = (const float*)d_in[0];
  const float* w1   = (const float*)d_in[1];
  const float* b1   = (const float*)d_in[2];
  const float* w2   = (const float*)d_in[3];
  const float* b2   = (const float*)d_in[4];
  const float* wih  = (const float*)d_in[5];
  const float* whh  = (const float*)d_in[6];
  const float* bih  = (const float*)d_in[7];
  const float* bhh  = (const float*)d_in[8];
  const int*   batch= (const int*)d_in[9];
  const int N = in_sizes[9];

  char* ws = (char*)d_ws;
  short* w1bf   = (short*)(ws + 0);            // 128 KB
  short* wihbf  = (short*)(ws + (1u<<17));     // 384 KB @128K
  short* whhbf  = (short*)(ws + (1u<<19));     // 384 KB @512K
  float* counts = (float*)(ws + 917504);       // 16 KB @896K
  uint8_t* w1q  = (uint8_t*)(ws + 933888);     // 64 KB @912K
  float* pool   = (float*)(ws + (1u<<20));     // 4 MB @1M
  float* repr   = (float*)(ws + (1u<<20) + (1u<<22)); // 4 MB @5M
  float* sgate  = (float*)(ws + (9u<<20));     // 2 MB @9M
  uint32_t* hgp = (uint32_t*)(ws + (12u<<20)); // 2 MB @12M
  float* outp   = (float*)d_out;

  const size_t XBF_OFF = (size_t)16u << 20;              // 16 MB
  const size_t XQ_OFF  = XBF_OFF + ((size_t)272u << 20); // xbf 256MB (+pad) then xq
  const bool useXbf = ws_size >= XQ_OFF + (size_t)N * H; // xq = 128 MB
  short*   xbf = useXbf ? (short*)(ws + XBF_OFF) : nullptr;
  uint8_t* xq  = useXbf ? (uint8_t*)(ws + XQ_OFF) : nullptr;

  const int nTiles  = (N + TK - 1) / TK;       // 15625
  const int nChains = useXbf ? 640 : 512;      // fp8: 1280 blocks = 5/CU
  const int nBlk1a  = nChains * 2;
  const int nBlkP   = (N + TP0 - 1) / TP0;     // 3907

  conv_w<<<768, 256, 0, stream>>>(w1, wih, whh, w1bf, wihbf, whhbf, w1q, counts, pool);
  k0_pool<<<nBlkP, 512, 0, stream>>>(x, batch, pool, counts, xbf, xq, sgate, N);
  k0b_div<<<G*H/256, 256, 0, stream>>>(pool, counts, repr, pool);
  kT_hg<<<G/16, 256, 0, stream>>>(repr, w1bf, b1, hgp);

  for (int ts = 0; ts < 2; ++ts){
    if (useXbf){
      k1a_fp8<<<nBlk1a, 256, 0, stream>>>(xq, batch, hgp, w1q, w2, sgate, N, nTiles, nChains);
      k1b_pool<true><<<nBlkP, 512, 0, stream>>>(x, xbf, batch, sgate, b2, pool, N);
    } else {
      k1a_gate_f32<<<nBlk1a, 256, 0, stream>>>(x, batch, hgp, w1bf, w2, sgate, N, nTiles, nChains);
      k1b_pool<false><<<nBlkP, 512, 0, stream>>>(x, xbf, batch, sgate, b2, pool, N);
    }
    k2_gru<<<G/16, 256, 0, stream>>>(pool, counts, repr, wihbf, whhbf, bih, bhh,
                                     (ts == 0) ? repr : outp,
                                     w1bf, b1, hgp, (ts == 0) ? 1 : 0);
  }
}

// Round 15
// 668.135 us; speedup vs baseline: 1.3764x; 1.0462x over previous
//
#include <hip/hip_runtime.h>
#include <hip/hip_bf16.h>
#include <stdint.h>

#define H 256
#define G 4096
#define TK 32     // k1a tile rows
#define TP0 128   // k0/k1b tile rows

typedef __attribute__((ext_vector_type(8))) short bf16x8;
typedef __attribute__((ext_vector_type(4))) float f32x4;

__device__ inline short f2bf(float f){
  union { float f; uint32_t u; } v; v.f = f;
  uint32_t r = (v.u + 0x7FFFu + ((v.u >> 16) & 1u)) >> 16;
  return (short)(uint16_t)r;
}
__device__ inline float bf2f(short s){
  union { float f; uint32_t u; } v; v.u = ((uint32_t)(uint16_t)s) << 16;
  return v.f;
}
__device__ inline uint32_t pk2(float lo, float hi){
  return (uint32_t)(uint16_t)f2bf(lo) | ((uint32_t)(uint16_t)f2bf(hi) << 16);
}
__device__ inline uint32_t pkfp8(float4 v){
  int u = __builtin_amdgcn_cvt_pk_fp8_f32(v.x, v.y, 0, false);
  u = __builtin_amdgcn_cvt_pk_fp8_f32(v.z, v.w, u, true);
  return (uint32_t)u;
}
__device__ inline float sigmoidf_(float x){ return 1.f / (1.f + __expf(-x)); }

// LDS-only barrier: does NOT drain vmcnt, so in-flight global loads continue.
__device__ inline void ldsbar(){
  asm volatile("s_waitcnt lgkmcnt(0)" ::: "memory");
  __builtin_amdgcn_s_barrier();
}

// ---------------- conv_w: weight conversions + zero counts/pool ----------------
__global__ void conv_w(const float* __restrict__ w1, const float* __restrict__ wih,
                       const float* __restrict__ whh,
                       short* __restrict__ o1, short* __restrict__ oih, short* __restrict__ ohh,
                       uint8_t* __restrict__ w1q,
                       float* __restrict__ counts, float* __restrict__ pool){
  int i = blockIdx.x * 256 + threadIdx.x;
  if (i < H*H) o1[i] = f2bf(w1[i]);
  if (i < 3*H*H){ oih[i] = f2bf(wih[i]); ohh[i] = f2bf(whh[i]); }
  if (i < H*H/4){
    float4 v = *(const float4*)(w1 + (size_t)i*4);
    *(uint32_t*)(w1q + (size_t)i*4) = pkfp8(v);
  }
  if (i < G) counts[i] = 0.f;
  for (int j = i; j < G*H; j += 768*256) pool[j] = 0.f;
}

// ---------------- K0: mean-pool + counts + write x_bf16 + x_fp8 + zero sgate ----------------
__global__ __launch_bounds__(512) __attribute__((amdgpu_waves_per_eu(2, 8)))
void k0_pool(const float* __restrict__ x, const int* __restrict__ batch,
             float* __restrict__ pool, float* __restrict__ counts,
             short* __restrict__ xbf, uint8_t* __restrict__ xq,
             float* __restrict__ sgate, int nNodes){
  __shared__ int   ng[TP0];
  __shared__ float Pacc[8][H];
  __shared__ float Cacc[8];
  __shared__ int   spanSh;

  const int t = threadIdx.x;
  const int base = blockIdx.x * TP0;
  const int c4 = (t & 63) * 4;
  const int r0 = (t >> 6) * 16;   // 8 row-groups of 16 rows

  float4 v[16];
  #pragma unroll
  for (int i = 0; i < 16; ++i){
    int node = base + r0 + i;
    if (node < nNodes) v[i] = *(const float4*)(x + (size_t)node*H + c4);
    else v[i] = make_float4(0.f,0.f,0.f,0.f);
  }

  { int gi = blockIdx.x * 512 + t; if (gi < nNodes) sgate[gi] = 0.f; }

  if (t < TP0) ng[t] = (base + t < nNodes) ? batch[base + t] : -1;
  for (int u = t; u < 8*H; u += 512) ((float*)Pacc)[u] = 0.f;
  if (t < 8) Cacc[t] = 0.f;
  __syncthreads();

  if (t == 0){
    int lg = ng[0];
    if (base + TP0 <= nNodes) lg = ng[TP0-1];
    else { for (int i = TP0-1; i > 0; --i){ if (ng[i] >= 0){ lg = ng[i]; break; } } }
    spanSh = (ng[0] >= 0) ? (lg - ng[0]) : -1;
  }

  if (xbf){
    #pragma unroll
    for (int i = 0; i < 16; ++i){
      int node = base + r0 + i;
      if (node < nNodes){
        ushort4 o;
        o.x = (uint16_t)f2bf(v[i].x); o.y = (uint16_t)f2bf(v[i].y);
        o.z = (uint16_t)f2bf(v[i].z); o.w = (uint16_t)f2bf(v[i].w);
        *(ushort4*)(xbf + (size_t)node*H + c4) = o;
        *(uint32_t*)(xq + (size_t)node*H + c4) = pkfp8(v[i]);
      }
    }
  }
  __syncthreads();

  const int g0 = ng[0];
  const bool useLds = (spanSh >= 0) && (spanSh < 8);

  float ax=0.f, ay=0.f, az=0.f, aw=0.f;
  int cur = ng[r0];
  if (cur >= 0){
    #pragma unroll
    for (int i = 0; i < 16; ++i){
      int g = ng[r0 + i];
      if (g < 0) break;
      if (g != cur){
        if (useLds){
          atomicAdd(&Pacc[cur-g0][c4], ax);   atomicAdd(&Pacc[cur-g0][c4+1], ay);
          atomicAdd(&Pacc[cur-g0][c4+2], az); atomicAdd(&Pacc[cur-g0][c4+3], aw);
        } else {
          atomicAdd(&pool[(size_t)cur*H + c4], ax);   atomicAdd(&pool[(size_t)cur*H + c4+1], ay);
          atomicAdd(&pool[(size_t)cur*H + c4+2], az); atomicAdd(&pool[(size_t)cur*H + c4+3], aw);
        }
        ax=ay=az=aw=0.f; cur = g;
      }
      ax += v[i].x; ay += v[i].y; az += v[i].z; aw += v[i].w;
    }
    if (useLds){
      atomicAdd(&Pacc[cur-g0][c4], ax);   atomicAdd(&Pacc[cur-g0][c4+1], ay);
      atomicAdd(&Pacc[cur-g0][c4+2], az); atomicAdd(&Pacc[cur-g0][c4+3], aw);
    } else {
      atomicAdd(&pool[(size_t)cur*H + c4], ax);   atomicAdd(&pool[(size_t)cur*H + c4+1], ay);
      atomicAdd(&pool[(size_t)cur*H + c4+2], az); atomicAdd(&pool[(size_t)cur*H + c4+3], aw);
    }
  }
  if (t < TP0 && ng[t] >= 0){
    if (useLds) atomicAdd(&Cacc[ng[t]-g0], 1.f);
    else        atomicAdd(&counts[ng[t]], 1.f);
  }
  __syncthreads();

  if (useLds){
    int nr = spanSh + 1;
    for (int u = t; u < nr*H; u += 512){
      int r = u >> 8, c = u & 255;
      float vv = Pacc[r][c];
      if (vv != 0.f) atomicAdd(&pool[(size_t)(g0+r)*H + c], vv);
    }
    if (t < nr && Cacc[t] != 0.f) atomicAdd(&counts[g0 + t], Cacc[t]);
  }
}

// ---------------- KT2: repr = pool/cnt (fused k0b); zero pool; hgp GEMM ----------------
__global__ __launch_bounds__(256) void kT2(float* __restrict__ pool,
    const float* __restrict__ counts, float* __restrict__ repr,
    const short* __restrict__ w1bf, const float* __restrict__ b1,
    uint32_t* __restrict__ hgp){
  __shared__ short Ar[16][H + 8];
  const int t    = threadIdx.x;
  const int wid  = t >> 6;
  const int lane = t & 63;
  const int l15  = lane & 15;
  const int l4   = lane >> 4;
  const int g0   = blockIdx.x * 16;

  for (int u = t; u < 16*32; u += 256){
    int row = u >> 5, cg = u & 31;
    int c0 = cg * 8;
    int g = g0 + row;
    float cnt = fmaxf(counts[g], 1.f);
    float4* pp = (float4*)(pool + (size_t)g*H + c0);
    float4 p0 = pp[0], p1 = pp[1];
    p0.x/=cnt; p0.y/=cnt; p0.z/=cnt; p0.w/=cnt;
    p1.x/=cnt; p1.y/=cnt; p1.z/=cnt; p1.w/=cnt;
    float4* rp = (float4*)(repr + (size_t)g*H + c0);
    rp[0] = p0; rp[1] = p1;
    pp[0] = make_float4(0.f,0.f,0.f,0.f);
    pp[1] = make_float4(0.f,0.f,0.f,0.f);
    bf16x8 o;
    o[0]=f2bf(p0.x); o[1]=f2bf(p0.y); o[2]=f2bf(p0.z); o[3]=f2bf(p0.w);
    o[4]=f2bf(p1.x); o[5]=f2bf(p1.y); o[6]=f2bf(p1.z); o[7]=f2bf(p1.w);
    *(bf16x8*)(&Ar[row][c0]) = o;
  }
  __syncthreads();

  f32x4 acc[4];
  #pragma unroll
  for (int i = 0; i < 4; ++i) acc[i] = (f32x4){0.f,0.f,0.f,0.f};
  #pragma unroll
  for (int kc = 0; kc < 8; ++kc){
    bf16x8 a = *(bf16x8*)(&Ar[l15][kc*32 + l4*8]);
    #pragma unroll
    for (int nt = 0; nt < 4; ++nt){
      int col = wid*64 + nt*16 + l15;
      bf16x8 b = *(const bf16x8*)(w1bf + (size_t)col*H + kc*32 + l4*8);
      acc[nt] = __builtin_amdgcn_mfma_f32_16x16x32_bf16(a, b, acc[nt], 0, 0, 0);
    }
  }
  const float b1v0 = b1[wid*64 + l15];
  const float b1v1 = b1[wid*64 + 16 + l15];
  const float b1v2 = b1[wid*64 + 32 + l15];
  const float b1v3 = b1[wid*64 + 48 + l15];
  #pragma unroll
  for (int j = 0; j < 4; ++j){
    int row = l4*4 + j;
    hgp[(size_t)(g0+row)*128 + wid*32 + l15]      = pk2(acc[0][j]+b1v0, acc[1][j]+b1v1);
    hgp[(size_t)(g0+row)*128 + wid*32 + 16 + l15] = pk2(acc[2][j]+b1v2, acc[3][j]+b1v3);
  }
}

// ---------------- K1a-fp8: gate scores, FULL-COL persistent GEMM ----------------
// Each wave owns 64 cols (two 32-col groups A/B, acc regs reused). One barrier/tile.
// Per-wave partials atomicAdd directly to sgate (4 adds/node total).
__global__ __launch_bounds__(256) __attribute__((amdgpu_waves_per_eu(3, 4)))
void k1a_fp8(
    const uint8_t* __restrict__ xq, const int* __restrict__ batch,
    const uint32_t* __restrict__ hgp, const uint8_t* __restrict__ w1q,
    const float* __restrict__ w2, float* __restrict__ sgate,
    int nNodes, int nTiles, int nBlk){

  __shared__ uint8_t Ain[2][TK][H + 16];   // 272B pitch, 17.4 KB
  __shared__ int     ngS[2][TK];

  const int t    = threadIdx.x;
  const int wid  = t >> 6;      // 0..3 -> cols wid*64 .. wid*64+64
  const int lane = t & 63;
  const int l15  = lane & 15;
  const int l4   = lane >> 4;
  const int colB = wid*64;

  const int tile0 = (int)(((long long)blockIdx.x * nTiles) / nBlk);
  const int tile1 = (int)(((long long)(blockIdx.x+1) * nTiles) / nBlk);
  if (tile0 >= tile1) return;

  // W1 fp8 fragments for 64 cols: 4 sets x 8 longs = 64 VGPR
  long BfA0[8], BfA1[8], BfB0[8], BfB1[8];
  {
    const uint8_t* wp = w1q + (size_t)(colB + l15)*H + l4*8;
    #pragma unroll
    for (int kc = 0; kc < 8; ++kc){
      BfA0[kc] = *(const long*)(wp + kc*32);
      BfA1[kc] = *(const long*)(wp + 16*H + kc*32);
      BfB0[kc] = *(const long*)(wp + 32*H + kc*32);
      BfB1[kc] = *(const long*)(wp + 48*H + kc*32);
    }
  }
  const float w2A0 = w2[colB + l15];
  const float w2A1 = w2[colB + 16 + l15];
  const float w2B0 = w2[colB + 32 + l15];
  const float w2B1 = w2[colB + 48 + l15];

  const int srow  = t >> 4;        // 0..15
  const int scolB = (t & 15) * 16; // byte offset
  uint4 xv0, xv1;
  int ngv = -1;

  auto issueT = [&](int tile){
    int base = tile * TK;
    int n0 = base + srow, n1 = n0 + 16;
    xv0 = (n0 < nNodes) ? *(const uint4*)(xq + (size_t)n0*H + scolB) : make_uint4(0,0,0,0);
    xv1 = (n1 < nNodes) ? *(const uint4*)(xq + (size_t)n1*H + scolB) : make_uint4(0,0,0,0);
    if (t < TK){
      int node = base + t;
      ngv = (node < nNodes) ? batch[node] : -1;
    }
  };
  auto stageT = [&](int buf){
    *(uint4*)(&Ain[buf][srow][scolB])      = xv0;
    *(uint4*)(&Ain[buf][srow + 16][scolB]) = xv1;
    if (t < TK) ngS[buf][t] = ngv;
  };

  issueT(tile0);
  stageT(0);
  if (tile0 + 1 < tile1) issueT(tile0 + 1);

  int cur = 0;
  for (int tile = tile0; tile < tile1; ++tile, cur ^= 1){
    ldsbar();   // Ain[cur]/ngS[cur] visible; reads of Ain[cur^1] from prev iter done

    // ---- group A: cols colB..colB+32 ----
    uint32_t hvp[2][4];
    #pragma unroll
    for (int r = 0; r < 2; ++r)
      #pragma unroll
      for (int j = 0; j < 4; ++j){
        int g = ngS[cur][r*16 + l4*4 + j];
        hvp[r][j] = (g >= 0) ? hgp[(size_t)g*128 + wid*32 + l15] : 0u;
      }

    f32x4 acc0[2], acc1[2];
    #pragma unroll
    for (int r = 0; r < 2; ++r){ acc0[r] = (f32x4){0.f,0.f,0.f,0.f}; acc1[r] = (f32x4){0.f,0.f,0.f,0.f}; }
    #pragma unroll
    for (int kc = 0; kc < 8; ++kc){
      #pragma unroll
      for (int r = 0; r < 2; ++r){
        long a = *(const long*)(&Ain[cur][r*16 + l15][kc*32 + l4*8]);
        acc0[r] = __builtin_amdgcn_mfma_f32_16x16x32_fp8_fp8(a, BfA0[kc], acc0[r], 0, 0, 0);
        acc1[r] = __builtin_amdgcn_mfma_f32_16x16x32_fp8_fp8(a, BfA1[kc], acc1[r], 0, 0, 0);
      }
    }

    // stage next tile into other buffer; issue loads for tile+2
    if (tile + 1 < tile1){
      stageT(cur ^ 1);
      if (tile + 2 < tile1) issueT(tile + 2);
    }

    float p[2][4];
    #pragma unroll
    for (int r = 0; r < 2; ++r)
      #pragma unroll
      for (int j = 0; j < 4; ++j){
        float h0 = fmaxf(acc0[r][j] + bf2f((short)(uint16_t)(hvp[r][j] & 0xFFFFu)), 0.f);
        float h1 = fmaxf(acc1[r][j] + bf2f((short)(uint16_t)(hvp[r][j] >> 16)), 0.f);
        p[r][j] = w2A0*h0 + w2A1*h1;
      }

    // ---- group B: cols colB+32..colB+64 (acc regs reused) ----
    #pragma unroll
    for (int r = 0; r < 2; ++r)
      #pragma unroll
      for (int j = 0; j < 4; ++j){
        int g = ngS[cur][r*16 + l4*4 + j];
        hvp[r][j] = (g >= 0) ? hgp[(size_t)g*128 + wid*32 + 16 + l15] : 0u;
      }
    #pragma unroll
    for (int r = 0; r < 2; ++r){ acc0[r] = (f32x4){0.f,0.f,0.f,0.f}; acc1[r] = (f32x4){0.f,0.f,0.f,0.f}; }
    #pragma unroll
    for (int kc = 0; kc < 8; ++kc){
      #pragma unroll
      for (int r = 0; r < 2; ++r){
        long a = *(const long*)(&Ain[cur][r*16 + l15][kc*32 + l4*8]);
        acc0[r] = __builtin_amdgcn_mfma_f32_16x16x32_fp8_fp8(a, BfB0[kc], acc0[r], 0, 0, 0);
        acc1[r] = __builtin_amdgcn_mfma_f32_16x16x32_fp8_fp8(a, BfB1[kc], acc1[r], 0, 0, 0);
      }
    }
    #pragma unroll
    for (int r = 0; r < 2; ++r)
      #pragma unroll
      for (int j = 0; j < 4; ++j){
        float h0 = fmaxf(acc0[r][j] + bf2f((short)(uint16_t)(hvp[r][j] & 0xFFFFu)), 0.f);
        float h1 = fmaxf(acc1[r][j] + bf2f((short)(uint16_t)(hvp[r][j] >> 16)), 0.f);
        p[r][j] += w2B0*h0 + w2B1*h1;
      }

    // ---- reduce over 16 lanes (cols) and atomic per node ----
    #pragma unroll
    for (int off = 1; off < 16; off <<= 1){
      #pragma unroll
      for (int r = 0; r < 2; ++r)
        #pragma unroll
        for (int j = 0; j < 4; ++j) p[r][j] += __shfl_xor(p[r][j], off);
    }
    if (l15 == 0){
      int base = tile * TK;
      #pragma unroll
      for (int r = 0; r < 2; ++r)
        #pragma unroll
        for (int j = 0; j < 4; ++j){
          int idx = r*16 + l4*4 + j;
          if (ngS[cur][idx] >= 0)
            atomicAdd(&sgate[base + idx], p[r][j]);
        }
    }
  }
}

// ---------------- K1b: streaming weighted pooling (128-row tiles); zeroes sgate ----------------
template<bool BF>
__global__ __launch_bounds__(512) __attribute__((amdgpu_waves_per_eu(2, 8)))
void k1b_pool(
    const float* __restrict__ xf32, const short* __restrict__ xbf,
    const int* __restrict__ batch, float* __restrict__ sgate,
    const float* __restrict__ b2p, float* __restrict__ pool, int nNodes){

  __shared__ int   ng[TP0];
  __shared__ float gs[TP0];
  __shared__ float Pacc[8][H];
  __shared__ int   spanSh;

  const int t = threadIdx.x;
  const int base = blockIdx.x * TP0;
  const int c4 = (t & 63) * 4;
  const int r0 = (t >> 6) * 16;

  ushort4 u[16];
  float4  vf[16];
  #pragma unroll
  for (int i = 0; i < 16; ++i){
    int node = base + r0 + i;
    if constexpr (BF){
      u[i] = (node < nNodes) ? *(const ushort4*)(xbf + (size_t)node*H + c4)
                             : make_ushort4(0,0,0,0);
    } else {
      vf[i] = (node < nNodes) ? *(const float4*)(xf32 + (size_t)node*H + c4)
                              : make_float4(0.f,0.f,0.f,0.f);
    }
  }

  const float b2v = b2p[0];
  if (t < TP0){
    int node = base + t;
    if (node < nNodes){
      ng[t] = batch[node];
      gs[t] = sigmoidf_(sgate[node] + b2v);
      sgate[node] = 0.f;                 // ready for next k1a pass
    } else { ng[t] = -1; gs[t] = 0.f; }
  }
  for (int w = t; w < 8*H; w += 512) ((float*)Pacc)[w] = 0.f;
  __syncthreads();

  if (t == 0){
    int lg = ng[0];
    if (base + TP0 <= nNodes) lg = ng[TP0-1];
    else { for (int i = TP0-1; i > 0; --i){ if (ng[i] >= 0){ lg = ng[i]; break; } } }
    spanSh = (ng[0] >= 0) ? (lg - ng[0]) : -1;
  }
  __syncthreads();

  const int g0 = ng[0];
  const bool useLds = (spanSh >= 0) && (spanSh < 8);

  float ax=0.f, ay=0.f, az=0.f, aw=0.f;
  int cur = ng[r0];
  if (cur >= 0){
    #pragma unroll
    for (int i = 0; i < 16; ++i){
      int g = ng[r0 + i];
      if (g < 0) break;
      if (g != cur){
        if (useLds){
          atomicAdd(&Pacc[cur-g0][c4], ax);   atomicAdd(&Pacc[cur-g0][c4+1], ay);
          atomicAdd(&Pacc[cur-g0][c4+2], az); atomicAdd(&Pacc[cur-g0][c4+3], aw);
        } else {
          atomicAdd(&pool[(size_t)cur*H + c4], ax);   atomicAdd(&pool[(size_t)cur*H + c4+1], ay);
          atomicAdd(&pool[(size_t)cur*H + c4+2], az); atomicAdd(&pool[(size_t)cur*H + c4+3], aw);
        }
        ax=ay=az=aw=0.f; cur = g;
      }
      float gv = gs[r0 + i];
      if constexpr (BF){
        ax += gv * bf2f((short)u[i].x); ay += gv * bf2f((short)u[i].y);
        az += gv * bf2f((short)u[i].z); aw += gv * bf2f((short)u[i].w);
      } else {
        ax += gv * bf2f(f2bf(vf[i].x)); ay += gv * bf2f(f2bf(vf[i].y));
        az += gv * bf2f(f2bf(vf[i].z)); aw += gv * bf2f(f2bf(vf[i].w));
      }
    }
    if (useLds){
      atomicAdd(&Pacc[cur-g0][c4], ax);   atomicAdd(&Pacc[cur-g0][c4+1], ay);
      atomicAdd(&Pacc[cur-g0][c4+2], az); atomicAdd(&Pacc[cur-g0][c4+3], aw);
    } else {
      atomicAdd(&pool[(size_t)cur*H + c4], ax);   atomicAdd(&pool[(size_t)cur*H + c4+1], ay);
      atomicAdd(&pool[(size_t)cur*H + c4+2], az); atomicAdd(&pool[(size_t)cur*H + c4+3], aw);
    }
  }
  __syncthreads();

  if (useLds){
    int nr = spanSh + 1;
    for (int w = t; w < nr*H; w += 512){
      int r = w >> 8, c = w & 255;
      float vv = Pacc[r][c];
      if (vv != 0.f) atomicAdd(&pool[(size_t)(g0+r)*H + c], vv);
    }
  }
}

// ---------------- legacy bf16 k1a (fallback when ws too small for xq) ----------------
__global__ __launch_bounds__(256) __attribute__((amdgpu_waves_per_eu(3, 4)))
void k1a_gate_f32(
    const float* __restrict__ xf32, const int* __restrict__ batch,
    const uint32_t* __restrict__ hgp, const short* __restrict__ w1bf,
    const float* __restrict__ w2, float* __restrict__ sgate,
    int nNodes, int nTiles, int nChains){

  __shared__ short Ain[2][TK][H + 8];
  __shared__ int   ngS[2][TK];

  const int t    = threadIdx.x;
  const int wid  = t >> 6;
  const int lane = t & 63;
  const int l15  = lane & 15;
  const int l4   = lane >> 4;

  const int ch    = blockIdx.x >= nChains;
  const int chain = ch ? blockIdx.x - nChains : blockIdx.x;
  const int colB  = ch*128 + wid*32;
  const int hgcol = ch*64 + wid*16 + l15;

  const int tile0 = (int)(((long long)chain * nTiles) / nChains);
  const int tile1 = (int)(((long long)(chain+1) * nTiles) / nChains);
  if (tile0 >= tile1) return;

  bf16x8 Bf0[8], Bf1[8];
  {
    const short* wp0 = w1bf + (size_t)(colB + l15)*H + l4*8;
    #pragma unroll
    for (int kc = 0; kc < 8; ++kc){
      Bf0[kc] = *(const bf16x8*)(wp0 + kc*32);
      Bf1[kc] = *(const bf16x8*)(wp0 + 16*H + kc*32);
    }
  }
  const float w2v0 = w2[colB + l15];
  const float w2v1 = w2[colB + 16 + l15];

  const int srow = t >> 5;
  const int scol = (t & 31) * 8;
  float4 xf[4][2];
  int ngv = -1;

  auto issueT = [&](int tile){
    int base = tile * TK;
    #pragma unroll
    for (int q = 0; q < 4; ++q){
      int node = base + srow + q*8;
      if (node < nNodes){
        const float4* xp = (const float4*)(xf32 + (size_t)node*H + scol);
        xf[q][0] = xp[0]; xf[q][1] = xp[1];
      } else { xf[q][0] = make_float4(0.f,0.f,0.f,0.f); xf[q][1] = make_float4(0.f,0.f,0.f,0.f); }
    }
    if (t < TK){
      int node = base + t;
      ngv = (node < nNodes) ? batch[node] : -1;
    }
  };
  auto stageT = [&](int buf){
    #pragma unroll
    for (int q = 0; q < 4; ++q){
      bf16x8 o;
      float4 a = xf[q][0], c = xf[q][1];
      o[0]=f2bf(a.x); o[1]=f2bf(a.y); o[2]=f2bf(a.z); o[3]=f2bf(a.w);
      o[4]=f2bf(c.x); o[5]=f2bf(c.y); o[6]=f2bf(c.z); o[7]=f2bf(c.w);
      *(bf16x8*)(&Ain[buf][srow + q*8][scol]) = o;
    }
    if (t < TK) ngS[buf][t] = ngv;
  };

  issueT(tile0);
  stageT(0);
  if (tile0 + 1 < tile1) issueT(tile0 + 1);

  int cur = 0;
  for (int tile = tile0; tile < tile1; ++tile, cur ^= 1){
    ldsbar();

    int gr[2][4];
    uint32_t hvp[2][4];
    #pragma unroll
    for (int r = 0; r < 2; ++r)
      #pragma unroll
      for (int j = 0; j < 4; ++j){
        int g = ngS[cur][r*16 + l4*4 + j];
        gr[r][j] = g;
        hvp[r][j] = (g >= 0) ? hgp[(size_t)g*128 + hgcol] : 0u;
      }

    f32x4 acc0[2], acc1[2];
    #pragma unroll
    for (int r = 0; r < 2; ++r){ acc0[r] = (f32x4){0.f,0.f,0.f,0.f}; acc1[r] = (f32x4){0.f,0.f,0.f,0.f}; }
    #pragma unroll
    for (int kc = 0; kc < 8; ++kc){
      #pragma unroll
      for (int r = 0; r < 2; ++r){
        bf16x8 a = *(bf16x8*)(&Ain[cur][r*16 + l15][kc*32 + l4*8]);
        acc0[r] = __builtin_amdgcn_mfma_f32_16x16x32_bf16(a, Bf0[kc], acc0[r], 0, 0, 0);
        acc1[r] = __builtin_amdgcn_mfma_f32_16x16x32_bf16(a, Bf1[kc], acc1[r], 0, 0, 0);
      }
    }

    if (tile + 1 < tile1){
      stageT(cur ^ 1);
      if (tile + 2 < tile1) issueT(tile + 2);
    }

    float p[2][4];
    #pragma unroll
    for (int r = 0; r < 2; ++r)
      #pragma unroll
      for (int j = 0; j < 4; ++j){
        float h0 = fmaxf(acc0[r][j] + bf2f((short)(uint16_t)(hvp[r][j] & 0xFFFFu)), 0.f);
        float h1 = fmaxf(acc1[r][j] + bf2f((short)(uint16_t)(hvp[r][j] >> 16)), 0.f);
        p[r][j] = w2v0*h0 + w2v1*h1;
      }
    #pragma unroll
    for (int off = 1; off < 16; off <<= 1){
      #pragma unroll
      for (int r = 0; r < 2; ++r)
        #pragma unroll
        for (int j = 0; j < 4; ++j) p[r][j] += __shfl_xor(p[r][j], off);
    }
    if (l15 == 0){
      int base = tile * TK;
      #pragma unroll
      for (int r = 0; r < 2; ++r)
        #pragma unroll
        for (int j = 0; j < 4; ++j){
          if (gr[r][j] >= 0)
            atomicAdd(&sgate[base + r*16 + l4*4 + j], p[r][j]);
        }
    }
  }
}

// ---------------- K2: fused GRU (+ optional hgp for next ts); zeroes pool ----------------
__global__ __launch_bounds__(256) void k2_gru(float* __restrict__ pool,
    const float* __restrict__ counts, const float* __restrict__ repr_in,
    const short* __restrict__ wihbf, const short* __restrict__ whhbf,
    const float* __restrict__ bih, const float* __restrict__ bhh,
    float* __restrict__ repr_out,
    const short* __restrict__ w1bf, const float* __restrict__ b1,
    uint32_t* __restrict__ hgp, int doHg){

  __shared__ short Anew[16][H + 8];
  __shared__ short Aold[16][H + 8];
  __shared__ float hold[16][H];
  __shared__ float srz[16][2*H];
  __shared__ float sni[16][H];
  __shared__ float snh[16][H];

  const int t    = threadIdx.x;
  const int wid  = t >> 6;
  const int lane = t & 63;
  const int l15  = lane & 15;
  const int l4   = lane >> 4;
  const int g0   = blockIdx.x * 16;

  for (int u = t; u < 16*H; u += 256){
    int row = u >> 8, c = u & 255;
    int g = g0 + row;
    float cnt = fmaxf(counts[g], 1.f);
    float rin = repr_in[(size_t)g*H + c];
    float nr  = pool[(size_t)g*H + c] / cnt;
    pool[(size_t)g*H + c] = 0.f;
    Anew[row][c] = f2bf(nr);
    Aold[row][c] = f2bf(rin);
    hold[row][c] = rin;
  }
  __syncthreads();

  f32x4 ai[12], ah[12];
  #pragma unroll
  for (int i = 0; i < 12; ++i){ ai[i] = (f32x4){0.f,0.f,0.f,0.f}; ah[i] = (f32x4){0.f,0.f,0.f,0.f}; }

  for (int kc = 0; kc < 8; ++kc){
    bf16x8 an = *(bf16x8*)(&Anew[l15][kc*32 + l4*8]);
    bf16x8 ao = *(bf16x8*)(&Aold[l15][kc*32 + l4*8]);
    #pragma unroll
    for (int nt = 0; nt < 12; ++nt){
      int n = wid*192 + nt*16 + l15;
      bf16x8 bi = *(const bf16x8*)(wihbf + (size_t)n*H + kc*32 + l4*8);
      bf16x8 bh = *(const bf16x8*)(whhbf + (size_t)n*H + kc*32 + l4*8);
      ai[nt] = __builtin_amdgcn_mfma_f32_16x16x32_bf16(an, bi, ai[nt], 0, 0, 0);
      ah[nt] = __builtin_amdgcn_mfma_f32_16x16x32_bf16(ao, bh, ah[nt], 0, 0, 0);
    }
  }

  #pragma unroll
  for (int nt = 0; nt < 12; ++nt){
    int n = wid*192 + nt*16 + l15;
    float bi = bih[n], bh = bhh[n];
    #pragma unroll
    for (int r = 0; r < 4; ++r){
      int row = l4*4 + r;
      float si = ai[nt][r] + bi;
      float sh = ah[nt][r] + bh;
      if (n < 2*H) srz[row][n] = si + sh;
      else { sni[row][n - 2*H] = si; snh[row][n - 2*H] = sh; }
    }
  }
  __syncthreads();

  for (int u = t; u < 16*H; u += 256){
    int row = u >> 8, c = u & 255;
    float rr = sigmoidf_(srz[row][c]);
    float zz = sigmoidf_(srz[row][H + c]);
    float nn = tanhf(sni[row][c] + rr * snh[row][c]);
    float hv = (1.f - zz) * nn + zz * hold[row][c];
    float out = fmaxf(hv, 0.f);
    repr_out[(size_t)(g0 + row)*H + c] = out;
    Anew[row][c] = f2bf(out);
  }

  if (doHg){
    __syncthreads();
    f32x4 acc[4];
    #pragma unroll
    for (int i = 0; i < 4; ++i) acc[i] = (f32x4){0.f,0.f,0.f,0.f};
    #pragma unroll
    for (int kc = 0; kc < 8; ++kc){
      bf16x8 a = *(bf16x8*)(&Anew[l15][kc*32 + l4*8]);
      #pragma unroll
      for (int nt = 0; nt < 4; ++nt){
        int col = wid*64 + nt*16 + l15;
        bf16x8 b = *(const bf16x8*)(w1bf + (size_t)col*H + kc*32 + l4*8);
        acc[nt] = __builtin_amdgcn_mfma_f32_16x16x32_bf16(a, b, acc[nt], 0, 0, 0);
      }
    }
    const float b1v0 = b1[wid*64 + l15];
    const float b1v1 = b1[wid*64 + 16 + l15];
    const float b1v2 = b1[wid*64 + 32 + l15];
    const float b1v3 = b1[wid*64 + 48 + l15];
    #pragma unroll
    for (int j = 0; j < 4; ++j){
      int row = l4*4 + j;
      hgp[(size_t)(g0+row)*128 + wid*32 + l15]      = pk2(acc[0][j]+b1v0, acc[1][j]+b1v1);
      hgp[(size_t)(g0+row)*128 + wid*32 + 16 + l15] = pk2(acc[2][j]+b1v2, acc[3][j]+b1v3);
    }
  }
}

extern "C" void kernel_launch(void* const* d_in, const int* in_sizes, int n_in,
                              void* d_out, int out_size, void* d_ws, size_t ws_size,
                              hipStream_t stream){
  const float* x    = (const float*)d_in[0];
  const float* w1   = (const float*)d_in[1];
  const float* b1   = (const float*)d_in[2];
  const float* w2   = (const float*)d_in[3];
  const float* b2   = (const float*)d_in[4];
  const float* wih  = (const float*)d_in[5];
  const float* whh  = (const float*)d_in[6];
  const float* bih  = (const float*)d_in[7];
  const float* bhh  = (const float*)d_in[8];
  const int*   batch= (const int*)d_in[9];
  const int N = in_sizes[9];

  char* ws = (char*)d_ws;
  short* w1bf   = (short*)(ws + 0);            // 128 KB
  short* wihbf  = (short*)(ws + (1u<<17));     // 384 KB @128K
  short* whhbf  = (short*)(ws + (1u<<19));     // 384 KB @512K
  float* counts = (float*)(ws + 917504);       // 16 KB @896K
  uint8_t* w1q  = (uint8_t*)(ws + 933888);     // 64 KB @912K
  float* pool   = (float*)(ws + (1u<<20));     // 4 MB @1M
  float* repr   = (float*)(ws + (1u<<20) + (1u<<22)); // 4 MB @5M
  float* sgate  = (float*)(ws + (9u<<20));     // 2 MB @9M
  uint32_t* hgp = (uint32_t*)(ws + (12u<<20)); // 2 MB @12M
  float* outp   = (float*)d_out;

  const size_t XBF_OFF = (size_t)16u << 20;              // 16 MB
  const size_t XQ_OFF  = XBF_OFF + ((size_t)272u << 20); // xbf 256MB (+pad) then xq
  const bool useXbf = ws_size >= XQ_OFF + (size_t)N * H; // xq = 128 MB
  short*   xbf = useXbf ? (short*)(ws + XBF_OFF) : nullptr;
  uint8_t* xq  = useXbf ? (uint8_t*)(ws + XQ_OFF) : nullptr;

  const int nTiles  = (N + TK - 1) / TK;       // 15625
  const int nBlk1a  = 1024;                    // full-col fp8: 4 blocks/CU
  const int nChainsF= 512;                     // fallback bf16 col-half grid
  const int nBlkP   = (N + TP0 - 1) / TP0;     // 3907

  conv_w<<<768, 256, 0, stream>>>(w1, wih, whh, w1bf, wihbf, whhbf, w1q, counts, pool);
  k0_pool<<<nBlkP, 512, 0, stream>>>(x, batch, pool, counts, xbf, xq, sgate, N);
  kT2<<<G/16, 256, 0, stream>>>(pool, counts, repr, w1bf, b1, hgp);

  for (int ts = 0; ts < 2; ++ts){
    if (useXbf){
      k1a_fp8<<<nBlk1a, 256, 0, stream>>>(xq, batch, hgp, w1q, w2, sgate, N, nTiles, nBlk1a);
      k1b_pool<true><<<nBlkP, 512, 0, stream>>>(x, xbf, batch, sgate, b2, pool, N);
    } else {
      k1a_gate_f32<<<nChainsF*2, 256, 0, stream>>>(x, batch, hgp, w1bf, w2, sgate, N, nTiles, nChainsF);
      k1b_pool<false><<<nBlkP, 512, 0, stream>>>(x, xbf, batch, sgate, b2, pool, N);
    }
    k2_gru<<<G/16, 256, 0, stream>>>(pool, counts, repr, wihbf, whhbf, bih, bhh,
                                     (ts == 0) ? repr : outp,
                                     w1bf, b1, hgp, (ts == 0) ? 1 : 0);
  }
}